// Round 4
// baseline (777.071 us; speedup 1.0000x reference)
//
#include <hip/hip_runtime.h>
#include <hip/hip_bf16.h>

#define N_NODES 100000
#define M_PAD   100096            // 782 * 128, padded row count for MFMA GEMM
#define N_EDGES 1600000
#define E_TOT   (N_EDGES + N_NODES)   // + self loops
#define NEG_SLOPE 0.2f

#define G_NODES 128                                  // nodes per bucket (pow2)
#define BUCKETS ((N_NODES + G_NODES - 1) / G_NODES)  // 782

typedef __attribute__((ext_vector_type(8))) short s16x8;
typedef __attribute__((ext_vector_type(4))) float f32x4;

__device__ __forceinline__ float lo16(unsigned u) { return __uint_as_float(u << 16); }
__device__ __forceinline__ float hi16(unsigned u) { return __uint_as_float(u & 0xffff0000u); }

// ---------------- CSR build: 2-level binning (write-locality) ----------------

// P1a: histogram of dst-buckets, LDS-reduced
__global__ __launch_bounds__(256) void bucket_count_kernel(const int* __restrict__ ei,
                                                           int* __restrict__ bcnt) {
    __shared__ int h[BUCKETS];
    for (int i = threadIdx.x; i < BUCKETS; i += 256) h[i] = 0;
    __syncthreads();
    int stride = gridDim.x * 256;
    for (int e = blockIdx.x * 256 + threadIdx.x; e < E_TOT; e += stride) {
        int d = (e < N_EDGES) ? ei[N_EDGES + e] : e - N_EDGES;
        atomicAdd(&h[d >> 7], 1);
    }
    __syncthreads();
    for (int i = threadIdx.x; i < BUCKETS; i += 256)
        if (h[i]) atomicAdd(&bcnt[i], h[i]);
}

// scan of bucket counts (single block)
__global__ __launch_bounds__(1024) void bucket_scan_kernel(const int* __restrict__ bcnt,
                                                           int* __restrict__ boff,
                                                           int* __restrict__ bcur) {
    __shared__ int lds[1024];
    int tid = threadIdx.x;
    int v = (tid < BUCKETS) ? bcnt[tid] : 0;
    lds[tid] = v;
    __syncthreads();
    for (int off = 1; off < 1024; off <<= 1) {
        int t = (tid >= off) ? lds[tid - off] : 0;
        __syncthreads();
        lds[tid] += t;
        __syncthreads();
    }
    int excl = lds[tid] - v;
    if (tid < BUCKETS) { boff[tid] = excl; bcur[tid] = excl; }
    if (tid == 0) boff[BUCKETS] = E_TOT;
}

// P1b: scatter (s,d) into bucket-contiguous tmp regions (append => line-coherent writes)
__global__ __launch_bounds__(256) void bucket_scatter_kernel(const int* __restrict__ ei,
                                                             int* __restrict__ bcur,
                                                             int2* __restrict__ tmp) {
    int e = blockIdx.x * 256 + threadIdx.x;
    if (e >= E_TOT) return;
    int s, d;
    if (e < N_EDGES) { s = ei[e]; d = ei[N_EDGES + e]; }
    else             { s = d = e - N_EDGES; }
    int pos = atomicAdd(&bcur[d >> 7], 1);
    tmp[pos] = make_int2(s, d);
}

// P2: per-bucket local count + scan -> rowptr; then place csr/csrd (L2-resident region)
__global__ __launch_bounds__(256) void bucket_build_kernel(const int2* __restrict__ tmp,
                                                           const int* __restrict__ boff,
                                                           int* __restrict__ rowptr,
                                                           int* __restrict__ csr,
                                                           int* __restrict__ csrd) {
    __shared__ int hcnt[G_NODES];
    __shared__ int hoff[G_NODES];
    int b = blockIdx.x;
    int base = boff[b], cnt = boff[b + 1] - base;
    int tid = threadIdx.x;
    if (tid < G_NODES) hcnt[tid] = 0;
    __syncthreads();
    for (int i = tid; i < cnt; i += 256)
        atomicAdd(&hcnt[tmp[base + i].y & (G_NODES - 1)], 1);
    __syncthreads();
    if (tid < G_NODES) hoff[tid] = hcnt[tid];
    __syncthreads();
    for (int off = 1; off < G_NODES; off <<= 1) {
        int t = (tid < G_NODES && tid >= off) ? hoff[tid - off] : 0;
        __syncthreads();
        if (tid < G_NODES) hoff[tid] += t;
        __syncthreads();
    }
    if (tid < G_NODES) {
        int excl = hoff[tid] - hcnt[tid];
        int node = b * G_NODES + tid;
        if (node < N_NODES) rowptr[node] = base + excl;
        hcnt[tid] = excl;       // reuse as cursor
    }
    __syncthreads();
    for (int i = tid; i < cnt; i += 256) {
        int2 e = tmp[base + i];
        int pos = base + atomicAdd(&hcnt[e.y & (G_NODES - 1)], 1);
        csr[pos] = e.x;
        csrd[pos] = e.y;
    }
    if (b == 0 && tid == 0) rowptr[N_NODES] = E_TOT;
}

// ---------------- dtype conversion ----------------

__global__ void cvt_x_kernel(const float* __restrict__ in, __hip_bfloat16* __restrict__ out, int n4) {
    int i = blockIdx.x * blockDim.x + threadIdx.x;
    if (i >= n4) return;
    float4 v = ((const float4*)in)[i];
    __hip_bfloat162 a, b;
    a.x = __float2bfloat16(v.x); a.y = __float2bfloat16(v.y);
    b.x = __float2bfloat16(v.z); b.y = __float2bfloat16(v.w);
    *(__hip_bfloat162*)&out[(size_t)i * 4]     = a;
    *(__hip_bfloat162*)&out[(size_t)i * 4 + 2] = b;
}

// W [K][Nc] f32 -> Wt [Nc][K] bf16
__global__ void cvt_wt_kernel(const float* __restrict__ W, __hip_bfloat16* __restrict__ Wt, int K, int Nc) {
    int idx = blockIdx.x * blockDim.x + threadIdx.x;
    if (idx >= K * Nc) return;
    int k = idx / Nc, n = idx - k * Nc;
    Wt[n * K + k] = __float2bfloat16(W[idx]);
}

// ---------------- MFMA GEMM: C[m, :] = A[m, :] @ Bt^T, K = 128 ----------------

template<int NCOLS>
__global__ __launch_bounds__(256) void mfma_gemm_kernel(const __hip_bfloat16* __restrict__ A,
                                                        const __hip_bfloat16* __restrict__ Bt,
                                                        __hip_bfloat16* __restrict__ C) {
    constexpr int CG = NCOLS / 32;           // 16-col groups per wave
    int wid = threadIdx.x >> 6;
    int lane = threadIdx.x & 63;
    int wr = wid >> 1, wc = wid & 1;
    int l15 = lane & 15, lk = lane >> 4;     // lk in 0..3

    s16x8 bfrag[CG][4];
    #pragma unroll
    for (int cg = 0; cg < CG; ++cg) {
        int col = wc * (NCOLS / 2) + cg * 16 + l15;
        #pragma unroll
        for (int ks = 0; ks < 4; ++ks)
            bfrag[cg][ks] = *(const s16x8*)&Bt[col * 128 + ks * 32 + lk * 8];
    }
    int rowblk = blockIdx.x * 128;
    #pragma unroll
    for (int st = 0; st < 4; ++st) {
        int rbase = rowblk + st * 32 + wr * 16;
        s16x8 afrag[4];
        #pragma unroll
        for (int ks = 0; ks < 4; ++ks)
            afrag[ks] = *(const s16x8*)&A[(size_t)(rbase + l15) * 128 + ks * 32 + lk * 8];
        f32x4 acc[CG];
        #pragma unroll
        for (int cg = 0; cg < CG; ++cg) acc[cg] = (f32x4){0.f, 0.f, 0.f, 0.f};
        #pragma unroll
        for (int ks = 0; ks < 4; ++ks) {
            #pragma unroll
            for (int cg = 0; cg < CG; ++cg)
                acc[cg] = __builtin_amdgcn_mfma_f32_16x16x32_bf16(afrag[ks], bfrag[cg][ks], acc[cg], 0, 0, 0);
        }
        #pragma unroll
        for (int cg = 0; cg < CG; ++cg) {
            int c = wc * (NCOLS / 2) + cg * 16 + l15;
            #pragma unroll
            for (int j = 0; j < 4; ++j)
                C[(size_t)(rbase + lk * 4 + j) * NCOLS + c] = __float2bfloat16(acc[cg][j]);
        }
    }
}

// ---------------- attention scores: s[n,h] = <h[n,h,:], att[h,:]> ----------------

template<int C, int J>
__global__ void score_kernel(const __hip_bfloat16* __restrict__ h, const float* __restrict__ att_src,
                             const float* __restrict__ att_dst,
                             float* __restrict__ s_src, float* __restrict__ s_dst, int n) {
    int idx = blockIdx.x * blockDim.x + threadIdx.x;   // node*4 + head
    if (idx >= n * 4) return;
    int node = idx >> 2, hd = idx & 3;
    const __hip_bfloat16* hp = h + (size_t)node * J + hd * C;
    const float* as = att_src + hd * C;
    const float* ad = att_dst + hd * C;
    float ss = 0.f, sd = 0.f;
    #pragma unroll
    for (int c8 = 0; c8 < C / 8; ++c8) {
        uint4 u = *(const uint4*)&hp[c8 * 8];   // 8 bf16
        const unsigned* uw = (const unsigned*)&u;
        #pragma unroll
        for (int t = 0; t < 4; ++t) {
            int c = c8 * 8 + t * 2;
            float v0 = lo16(uw[t]);
            float v1 = hi16(uw[t]);
            ss += v0 * as[c] + v1 * as[c + 1];
            sd += v0 * ad[c] + v1 * ad[c + 1];
        }
    }
    s_src[idx] = ss;
    s_dst[idx] = sd;
}

// ---------------- per-edge unnormalized softmax weights (CSR order) ----------------

__global__ void edge_p_kernel(const int* __restrict__ csr, const int* __restrict__ csrd,
                              const float* __restrict__ s_src, const float* __restrict__ s_dst,
                              float* __restrict__ p4, int etot) {
    int j = blockIdx.x * blockDim.x + threadIdx.x;
    if (j >= etot) return;
    int s = csr[j], d = csrd[j];
    float4 a = *(const float4*)&s_src[(size_t)s * 4];
    float4 b = *(const float4*)&s_dst[(size_t)d * 4];
    float4 r;
    float e;
    e = a.x + b.x; e = e > 0.f ? e : NEG_SLOPE * e; r.x = __expf(e);
    e = a.y + b.y; e = e > 0.f ? e : NEG_SLOPE * e; r.y = __expf(e);
    e = a.z + b.z; e = e > 0.f ? e : NEG_SLOPE * e; r.z = __expf(e);
    e = a.w + b.w; e = e > 0.f ? e : NEG_SLOPE * e; r.w = __expf(e);
    *(float4*)&p4[(size_t)j * 4] = r;
}

// ---------------- layer-1 aggregation (+bias +ELU), bf16 h ----------------

__global__ __launch_bounds__(256) void agg1_kernel(
        const __hip_bfloat16* __restrict__ h1, const float* __restrict__ p4,
        const int* __restrict__ rowptr, const int* __restrict__ csr,
        const float* __restrict__ b1, __hip_bfloat16* __restrict__ out1) {
    int d = blockIdx.x * 4 + (threadIdx.x >> 6);
    if (d >= N_NODES) return;
    int lane = threadIdx.x & 63;
    int c0 = lane * 2;
    int hd = lane >> 4;
    float accx = 0.f, accy = 0.f, z = 0.f;
    int beg = rowptr[d], end = rowptr[d + 1];
    int j = beg;
    for (; j + 3 < end; j += 4) {
        int s0 = csr[j], s1 = csr[j + 1], s2 = csr[j + 2], s3 = csr[j + 3];
        float q0 = p4[(size_t)(j + 0) * 4 + hd];
        float q1 = p4[(size_t)(j + 1) * 4 + hd];
        float q2 = p4[(size_t)(j + 2) * 4 + hd];
        float q3 = p4[(size_t)(j + 3) * 4 + hd];
        unsigned u0 = *(const unsigned*)&h1[(size_t)s0 * 128 + c0];
        unsigned u1 = *(const unsigned*)&h1[(size_t)s1 * 128 + c0];
        unsigned u2 = *(const unsigned*)&h1[(size_t)s2 * 128 + c0];
        unsigned u3 = *(const unsigned*)&h1[(size_t)s3 * 128 + c0];
        accx += q0 * lo16(u0) + q1 * lo16(u1) + q2 * lo16(u2) + q3 * lo16(u3);
        accy += q0 * hi16(u0) + q1 * hi16(u1) + q2 * hi16(u2) + q3 * hi16(u3);
        z += q0 + q1 + q2 + q3;
    }
    for (; j < end; ++j) {
        int s = csr[j];
        float q = p4[(size_t)j * 4 + hd];
        unsigned u = *(const unsigned*)&h1[(size_t)s * 128 + c0];
        accx += q * lo16(u);
        accy += q * hi16(u);
        z += q;
    }
    float invz = 1.0f / z;
    float vx = accx * invz + b1[c0];
    float vy = accy * invz + b1[c0 + 1];
    vx = vx > 0.f ? vx : __expf(vx) - 1.0f;   // ELU
    vy = vy > 0.f ? vy : __expf(vy) - 1.0f;
    __hip_bfloat162 o;
    o.x = __float2bfloat16(vx);
    o.y = __float2bfloat16(vy);
    *(__hip_bfloat162*)&out1[(size_t)d * 128 + c0] = o;
}

// ---------------- layer-2 aggregation + head mean + b2 + log_softmax, bf16 h ----------------

__global__ __launch_bounds__(256) void agg2_kernel(
        const __hip_bfloat16* __restrict__ h2, const float* __restrict__ p4,
        const int* __restrict__ rowptr, const int* __restrict__ csr,
        const float* __restrict__ b2, float* __restrict__ out) {
    int d = blockIdx.x * 4 + (threadIdx.x >> 6);
    if (d >= N_NODES) return;
    int lane = threadIdx.x & 63;
    bool active = lane < 40;
    int hd = lane / 10; if (hd > 3) hd = 3;
    float ax = 0.f, ay = 0.f, az = 0.f, aw = 0.f, z = 0.f;
    int beg = rowptr[d], end = rowptr[d + 1];
    int j = beg;
    for (; j + 3 < end; j += 4) {
        int s0 = csr[j], s1 = csr[j + 1], s2 = csr[j + 2], s3 = csr[j + 3];
        float q0 = p4[(size_t)(j + 0) * 4 + hd];
        float q1 = p4[(size_t)(j + 1) * 4 + hd];
        float q2 = p4[(size_t)(j + 2) * 4 + hd];
        float q3 = p4[(size_t)(j + 3) * 4 + hd];
        uint2 u0 = {0, 0}, u1 = {0, 0}, u2 = {0, 0}, u3 = {0, 0};
        if (active) {
            u0 = *(const uint2*)&h2[(size_t)s0 * 160 + lane * 4];
            u1 = *(const uint2*)&h2[(size_t)s1 * 160 + lane * 4];
            u2 = *(const uint2*)&h2[(size_t)s2 * 160 + lane * 4];
            u3 = *(const uint2*)&h2[(size_t)s3 * 160 + lane * 4];
        }
        ax += q0 * lo16(u0.x) + q1 * lo16(u1.x) + q2 * lo16(u2.x) + q3 * lo16(u3.x);
        ay += q0 * hi16(u0.x) + q1 * hi16(u1.x) + q2 * hi16(u2.x) + q3 * hi16(u3.x);
        az += q0 * lo16(u0.y) + q1 * lo16(u1.y) + q2 * lo16(u2.y) + q3 * lo16(u3.y);
        aw += q0 * hi16(u0.y) + q1 * hi16(u1.y) + q2 * hi16(u2.y) + q3 * hi16(u3.y);
        z += q0 + q1 + q2 + q3;
    }
    for (; j < end; ++j) {
        int s = csr[j];
        float q = p4[(size_t)j * 4 + hd];
        uint2 u = {0, 0};
        if (active) u = *(const uint2*)&h2[(size_t)s * 160 + lane * 4];
        ax += q * lo16(u.x);
        ay += q * hi16(u.x);
        az += q * lo16(u.y);
        aw += q * hi16(u.y);
        z += q;
    }
    float invz = 1.0f / z;
    float rx = ax * invz, ry = ay * invz, rz = az * invz, rw = aw * invz;
    float sx = rx + __shfl(rx, lane + 10) + __shfl(rx, lane + 20) + __shfl(rx, lane + 30);
    float sy = ry + __shfl(ry, lane + 10) + __shfl(ry, lane + 20) + __shfl(ry, lane + 30);
    float sz = rz + __shfl(rz, lane + 10) + __shfl(rz, lane + 20) + __shfl(rz, lane + 30);
    float sw = rw + __shfl(rw, lane + 10) + __shfl(rw, lane + 20) + __shfl(rw, lane + 30);
    int lc = lane < 10 ? lane : 9;
    float4 bb = *(const float4*)&b2[lc * 4];
    bool own = lane < 10;
    float vx = own ? sx * 0.25f + bb.x : -1e30f;
    float vy = own ? sy * 0.25f + bb.y : -1e30f;
    float vz = own ? sz * 0.25f + bb.z : -1e30f;
    float vw = own ? sw * 0.25f + bb.w : -1e30f;
    float m = fmaxf(fmaxf(vx, vy), fmaxf(vz, vw));
    #pragma unroll
    for (int off = 1; off < 16; off <<= 1) m = fmaxf(m, __shfl_xor(m, off));
    float ssum = 0.f;
    if (own) {
        ssum = __expf(vx - m) + __expf(vy - m) + __expf(vz - m) + __expf(vw - m);
    }
    #pragma unroll
    for (int off = 1; off < 16; off <<= 1) ssum += __shfl_xor(ssum, off);
    float lse = m + __logf(ssum);
    if (own) {
        float4 o = {vx - lse, vy - lse, vz - lse, vw - lse};
        *(float4*)&out[(size_t)d * 40 + lane * 4] = o;
    }
}

// ---------------- launch ----------------

extern "C" void kernel_launch(void* const* d_in, const int* in_sizes, int n_in,
                              void* d_out, int out_size, void* d_ws, size_t ws_size,
                              hipStream_t stream) {
    const float* x   = (const float*)d_in[0];
    const int*   ei  = (const int*)d_in[1];
    const float* W1  = (const float*)d_in[2];
    const float* as1 = (const float*)d_in[3];
    const float* ad1 = (const float*)d_in[4];
    const float* b1  = (const float*)d_in[5];
    const float* W2  = (const float*)d_in[6];
    const float* as2 = (const float*)d_in[7];
    const float* ad2 = (const float*)d_in[8];
    const float* b2  = (const float*)d_in[9];
    float* out = (float*)d_out;

    char* ws = (char*)d_ws;
    size_t off = 0;
    auto alloc = [&](size_t bytes) {
        void* p = ws + off;
        off += (bytes + 255) & ~(size_t)255;
        return p;
    };
    __hip_bfloat16* xb    = (__hip_bfloat16*)alloc((size_t)M_PAD * 128 * 2);
    __hip_bfloat16* h1b   = (__hip_bfloat16*)alloc((size_t)M_PAD * 128 * 2);
    __hip_bfloat16* out1b = (__hip_bfloat16*)alloc((size_t)M_PAD * 128 * 2);
    __hip_bfloat16* h2b   = (__hip_bfloat16*)alloc((size_t)M_PAD * 160 * 2);
    __hip_bfloat16* W1t   = (__hip_bfloat16*)alloc((size_t)128 * 128 * 2);
    __hip_bfloat16* W2t   = (__hip_bfloat16*)alloc((size_t)160 * 128 * 2);
    float* s_src1  = (float*)alloc((size_t)N_NODES * 4 * 4);
    float* s_dst1  = (float*)alloc((size_t)N_NODES * 4 * 4);
    float* s_src2  = (float*)alloc((size_t)N_NODES * 4 * 4);
    float* s_dst2  = (float*)alloc((size_t)N_NODES * 4 * 4);
    float* p4      = (float*)alloc((size_t)E_TOT * 4 * 4);
    int2*  tmp     = (int2*)alloc((size_t)E_TOT * 8);
    int*   rowptr  = (int*)alloc((size_t)(N_NODES + 1) * 4);
    int*   csr     = (int*)alloc((size_t)E_TOT * 4);
    int*   csrd    = (int*)alloc((size_t)E_TOT * 4);
    int*   bcnt    = (int*)alloc((size_t)BUCKETS * 4);
    int*   boff    = (int*)alloc((size_t)(BUCKETS + 1) * 4);
    int*   bcur    = (int*)alloc((size_t)BUCKETS * 4);

    // CSR build (2-level binning)
    hipMemsetAsync(bcnt, 0, (size_t)BUCKETS * 4, stream);
    bucket_count_kernel<<<416, 256, 0, stream>>>(ei, bcnt);
    bucket_scan_kernel<<<1, 1024, 0, stream>>>(bcnt, boff, bcur);
    bucket_scatter_kernel<<<(E_TOT + 255) / 256, 256, 0, stream>>>(ei, bcur, tmp);
    bucket_build_kernel<<<BUCKETS, 256, 0, stream>>>(tmp, boff, rowptr, csr, csrd);

    // dtype prep
    cvt_x_kernel<<<(N_NODES * 32 + 255) / 256, 256, 0, stream>>>(x, xb, N_NODES * 32);
    cvt_wt_kernel<<<(128 * 128 + 255) / 256, 256, 0, stream>>>(W1, W1t, 128, 128);
    cvt_wt_kernel<<<(128 * 160 + 255) / 256, 256, 0, stream>>>(W2, W2t, 128, 160);

    // layer 1
    mfma_gemm_kernel<128><<<M_PAD / 128, 256, 0, stream>>>(xb, W1t, h1b);
    score_kernel<32, 128><<<(N_NODES * 4 + 255) / 256, 256, 0, stream>>>(h1b, as1, ad1, s_src1, s_dst1, N_NODES);
    edge_p_kernel<<<(E_TOT + 255) / 256, 256, 0, stream>>>(csr, csrd, s_src1, s_dst1, p4, E_TOT);
    agg1_kernel<<<(N_NODES + 3) / 4, 256, 0, stream>>>(h1b, p4, rowptr, csr, b1, out1b);

    // layer 2
    mfma_gemm_kernel<160><<<M_PAD / 128, 256, 0, stream>>>(out1b, W2t, h2b);
    score_kernel<40, 160><<<(N_NODES * 4 + 255) / 256, 256, 0, stream>>>(h2b, as2, ad2, s_src2, s_dst2, N_NODES);
    edge_p_kernel<<<(E_TOT + 255) / 256, 256, 0, stream>>>(csr, csrd, s_src2, s_dst2, p4, E_TOT);
    agg2_kernel<<<(N_NODES + 3) / 4, 256, 0, stream>>>(h2b, p4, rowptr, csr, b2, out);
}

// Round 5
// 455.655 us; speedup vs baseline: 1.7054x; 1.7054x over previous
//
#include <hip/hip_runtime.h>
#include <hip/hip_bf16.h>

#define N_NODES 100000
#define M_PAD   100096            // 782 * 128, padded row count for MFMA GEMM
#define N_EDGES 1600000
#define E_TOT   (N_EDGES + N_NODES)   // + self loops
#define NEG_SLOPE 0.2f

#define G_NODES 128                                  // nodes per bucket (pow2)
#define BUCKETS ((N_NODES + G_NODES - 1) / G_NODES)  // 782
#define REP 256                                      // cursor replicas (slices)
#define SLICE ((E_TOT + REP - 1) / REP)              // 6641 edges per slice

typedef __attribute__((ext_vector_type(8))) short s16x8;
typedef __attribute__((ext_vector_type(4))) float f32x4;

__device__ __forceinline__ float lo16(unsigned u) { return __uint_as_float(u << 16); }
__device__ __forceinline__ float hi16(unsigned u) { return __uint_as_float(u & 0xffff0000u); }

// ---------------- CSR build: sliced counting-sort partition ----------------

// per-slice histogram of dst buckets (LDS atomics only; plain global stores)
__global__ __launch_bounds__(256) void slice_count_kernel(const int* __restrict__ ei,
                                                          int* __restrict__ cnt) {
    __shared__ int h[BUCKETS];
    for (int i = threadIdx.x; i < BUCKETS; i += 256) h[i] = 0;
    __syncthreads();
    int r = blockIdx.x;
    int lo = r * SLICE, hi = min(lo + SLICE, E_TOT);
    for (int e = lo + threadIdx.x; e < hi; e += 256) {
        int d = (e < N_EDGES) ? ei[N_EDGES + e] : e - N_EDGES;
        atomicAdd(&h[d >> 7], 1);
    }
    __syncthreads();
    for (int i = threadIdx.x; i < BUCKETS; i += 256)
        cnt[(size_t)r * BUCKETS + i] = h[i];
}

// exclusive scan down each bucket's column of slice counts (block = bucket)
__global__ __launch_bounds__(256) void col_scan_kernel(int* __restrict__ cnt,
                                                       int* __restrict__ bsum) {
    __shared__ int lds[REP];
    int b = blockIdx.x, tid = threadIdx.x;
    int v = cnt[(size_t)tid * BUCKETS + b];
    lds[tid] = v;
    __syncthreads();
    for (int off = 1; off < REP; off <<= 1) {
        int t = (tid >= off) ? lds[tid - off] : 0;
        __syncthreads();
        lds[tid] += t;
        __syncthreads();
    }
    cnt[(size_t)tid * BUCKETS + b] = lds[tid] - v;   // exclusive within column
    if (tid == REP - 1) bsum[b] = lds[tid];
}

// scan of bucket totals (single block)
__global__ __launch_bounds__(1024) void bucket_scan_kernel(const int* __restrict__ bsum,
                                                           int* __restrict__ boff) {
    __shared__ int lds[1024];
    int tid = threadIdx.x;
    int v = (tid < BUCKETS) ? bsum[tid] : 0;
    lds[tid] = v;
    __syncthreads();
    for (int off = 1; off < 1024; off <<= 1) {
        int t = (tid >= off) ? lds[tid - off] : 0;
        __syncthreads();
        lds[tid] += t;
        __syncthreads();
    }
    if (tid < BUCKETS) boff[tid] = lds[tid] - v;
    if (tid == 0) boff[BUCKETS] = E_TOT;
}

// cur[r][b] = boff[b] + colx[r][b]
__global__ __launch_bounds__(256) void cursor_init_kernel(const int* __restrict__ colx,
                                                          const int* __restrict__ boff,
                                                          int* __restrict__ cur) {
    int idx = blockIdx.x * 256 + threadIdx.x;
    if (idx >= REP * BUCKETS) return;
    int b = idx % BUCKETS;
    cur[idx] = boff[b] + colx[idx];
}

// scatter (s,d) into bucket-contiguous tmp; contention per cursor ~8.5
__global__ __launch_bounds__(256) void bucket_scatter_kernel(const int* __restrict__ ei,
                                                             int* __restrict__ cur,
                                                             int2* __restrict__ tmp) {
    int r = blockIdx.x;
    int lo = r * SLICE, hi = min(lo + SLICE, E_TOT);
    int* curr = cur + (size_t)r * BUCKETS;
    for (int e = lo + threadIdx.x; e < hi; e += 256) {
        int s, d;
        if (e < N_EDGES) { s = ei[e]; d = ei[N_EDGES + e]; }
        else             { s = d = e - N_EDGES; }
        int pos = atomicAdd(&curr[d >> 7], 1);
        tmp[pos] = make_int2(s, d);
    }
}

// per-bucket local count + scan -> rowptr; then place csr/csrd (L2-resident region)
__global__ __launch_bounds__(256) void bucket_build_kernel(const int2* __restrict__ tmp,
                                                           const int* __restrict__ boff,
                                                           int* __restrict__ rowptr,
                                                           int* __restrict__ csr,
                                                           int* __restrict__ csrd) {
    __shared__ int hcnt[G_NODES];
    __shared__ int hoff[G_NODES];
    int b = blockIdx.x;
    int base = boff[b], cnt = boff[b + 1] - base;
    int tid = threadIdx.x;
    if (tid < G_NODES) hcnt[tid] = 0;
    __syncthreads();
    for (int i = tid; i < cnt; i += 256)
        atomicAdd(&hcnt[tmp[base + i].y & (G_NODES - 1)], 1);
    __syncthreads();
    if (tid < G_NODES) hoff[tid] = hcnt[tid];
    __syncthreads();
    for (int off = 1; off < G_NODES; off <<= 1) {
        int t = (tid < G_NODES && tid >= off) ? hoff[tid - off] : 0;
        __syncthreads();
        if (tid < G_NODES) hoff[tid] += t;
        __syncthreads();
    }
    if (tid < G_NODES) {
        int excl = hoff[tid] - hcnt[tid];
        int node = b * G_NODES + tid;
        if (node < N_NODES) rowptr[node] = base + excl;
        hcnt[tid] = excl;       // reuse as cursor
    }
    __syncthreads();
    for (int i = tid; i < cnt; i += 256) {
        int2 e = tmp[base + i];
        int pos = base + atomicAdd(&hcnt[e.y & (G_NODES - 1)], 1);
        csr[pos] = e.x;
        csrd[pos] = e.y;
    }
    if (b == 0 && tid == 0) rowptr[N_NODES] = E_TOT;
}

// ---------------- dtype conversion ----------------

__global__ void cvt_x_kernel(const float* __restrict__ in, __hip_bfloat16* __restrict__ out, int n4) {
    int i = blockIdx.x * blockDim.x + threadIdx.x;
    if (i >= n4) return;
    float4 v = ((const float4*)in)[i];
    __hip_bfloat162 a, b;
    a.x = __float2bfloat16(v.x); a.y = __float2bfloat16(v.y);
    b.x = __float2bfloat16(v.z); b.y = __float2bfloat16(v.w);
    *(__hip_bfloat162*)&out[(size_t)i * 4]     = a;
    *(__hip_bfloat162*)&out[(size_t)i * 4 + 2] = b;
}

// W [K][Nc] f32 -> Wt [Nc][K] bf16
__global__ void cvt_wt_kernel(const float* __restrict__ W, __hip_bfloat16* __restrict__ Wt, int K, int Nc) {
    int idx = blockIdx.x * blockDim.x + threadIdx.x;
    if (idx >= K * Nc) return;
    int k = idx / Nc, n = idx - k * Nc;
    Wt[n * K + k] = __float2bfloat16(W[idx]);
}

// ---------------- MFMA GEMM: C[m, :] = A[m, :] @ Bt^T, K = 128 ----------------

template<int NCOLS>
__global__ __launch_bounds__(256) void mfma_gemm_kernel(const __hip_bfloat16* __restrict__ A,
                                                        const __hip_bfloat16* __restrict__ Bt,
                                                        __hip_bfloat16* __restrict__ C) {
    constexpr int CG = NCOLS / 32;           // 16-col groups per wave
    int wid = threadIdx.x >> 6;
    int lane = threadIdx.x & 63;
    int wr = wid >> 1, wc = wid & 1;
    int l15 = lane & 15, lk = lane >> 4;     // lk in 0..3

    s16x8 bfrag[CG][4];
    #pragma unroll
    for (int cg = 0; cg < CG; ++cg) {
        int col = wc * (NCOLS / 2) + cg * 16 + l15;
        #pragma unroll
        for (int ks = 0; ks < 4; ++ks)
            bfrag[cg][ks] = *(const s16x8*)&Bt[col * 128 + ks * 32 + lk * 8];
    }
    int rowblk = blockIdx.x * 128;
    #pragma unroll
    for (int st = 0; st < 4; ++st) {
        int rbase = rowblk + st * 32 + wr * 16;
        s16x8 afrag[4];
        #pragma unroll
        for (int ks = 0; ks < 4; ++ks)
            afrag[ks] = *(const s16x8*)&A[(size_t)(rbase + l15) * 128 + ks * 32 + lk * 8];
        f32x4 acc[CG];
        #pragma unroll
        for (int cg = 0; cg < CG; ++cg) acc[cg] = (f32x4){0.f, 0.f, 0.f, 0.f};
        #pragma unroll
        for (int ks = 0; ks < 4; ++ks) {
            #pragma unroll
            for (int cg = 0; cg < CG; ++cg)
                acc[cg] = __builtin_amdgcn_mfma_f32_16x16x32_bf16(afrag[ks], bfrag[cg][ks], acc[cg], 0, 0, 0);
        }
        #pragma unroll
        for (int cg = 0; cg < CG; ++cg) {
            int c = wc * (NCOLS / 2) + cg * 16 + l15;
            #pragma unroll
            for (int j = 0; j < 4; ++j)
                C[(size_t)(rbase + lk * 4 + j) * NCOLS + c] = __float2bfloat16(acc[cg][j]);
        }
    }
}

// ---------------- attention scores: s[n,h] = <h[n,h,:], att[h,:]> ----------------

template<int C, int J>
__global__ void score_kernel(const __hip_bfloat16* __restrict__ h, const float* __restrict__ att_src,
                             const float* __restrict__ att_dst,
                             float* __restrict__ s_src, float* __restrict__ s_dst, int n) {
    int idx = blockIdx.x * blockDim.x + threadIdx.x;   // node*4 + head
    if (idx >= n * 4) return;
    int node = idx >> 2, hd = idx & 3;
    const __hip_bfloat16* hp = h + (size_t)node * J + hd * C;
    const float* as = att_src + hd * C;
    const float* ad = att_dst + hd * C;
    float ss = 0.f, sd = 0.f;
    #pragma unroll
    for (int c8 = 0; c8 < C / 8; ++c8) {
        uint4 u = *(const uint4*)&hp[c8 * 8];   // 8 bf16
        const unsigned* uw = (const unsigned*)&u;
        #pragma unroll
        for (int t = 0; t < 4; ++t) {
            int c = c8 * 8 + t * 2;
            float v0 = lo16(uw[t]);
            float v1 = hi16(uw[t]);
            ss += v0 * as[c] + v1 * as[c + 1];
            sd += v0 * ad[c] + v1 * ad[c + 1];
        }
    }
    s_src[idx] = ss;
    s_dst[idx] = sd;
}

// ---------------- per-edge unnormalized softmax weights (CSR order) ----------------

__global__ void edge_p_kernel(const int* __restrict__ csr, const int* __restrict__ csrd,
                              const float* __restrict__ s_src, const float* __restrict__ s_dst,
                              float* __restrict__ p4, int etot) {
    int j = blockIdx.x * blockDim.x + threadIdx.x;
    if (j >= etot) return;
    int s = csr[j], d = csrd[j];
    float4 a = *(const float4*)&s_src[(size_t)s * 4];
    float4 b = *(const float4*)&s_dst[(size_t)d * 4];
    float4 r;
    float e;
    e = a.x + b.x; e = e > 0.f ? e : NEG_SLOPE * e; r.x = __expf(e);
    e = a.y + b.y; e = e > 0.f ? e : NEG_SLOPE * e; r.y = __expf(e);
    e = a.z + b.z; e = e > 0.f ? e : NEG_SLOPE * e; r.z = __expf(e);
    e = a.w + b.w; e = e > 0.f ? e : NEG_SLOPE * e; r.w = __expf(e);
    *(float4*)&p4[(size_t)j * 4] = r;
}

// ---------------- layer-1 aggregation (+bias +ELU), bf16 h ----------------

__global__ __launch_bounds__(256) void agg1_kernel(
        const __hip_bfloat16* __restrict__ h1, const float* __restrict__ p4,
        const int* __restrict__ rowptr, const int* __restrict__ csr,
        const float* __restrict__ b1, __hip_bfloat16* __restrict__ out1) {
    int d = blockIdx.x * 4 + (threadIdx.x >> 6);
    if (d >= N_NODES) return;
    int lane = threadIdx.x & 63;
    int c0 = lane * 2;
    int hd = lane >> 4;
    float accx = 0.f, accy = 0.f, z = 0.f;
    int beg = rowptr[d], end = rowptr[d + 1];
    int j = beg;
    for (; j + 3 < end; j += 4) {
        int s0 = csr[j], s1 = csr[j + 1], s2 = csr[j + 2], s3 = csr[j + 3];
        float q0 = p4[(size_t)(j + 0) * 4 + hd];
        float q1 = p4[(size_t)(j + 1) * 4 + hd];
        float q2 = p4[(size_t)(j + 2) * 4 + hd];
        float q3 = p4[(size_t)(j + 3) * 4 + hd];
        unsigned u0 = *(const unsigned*)&h1[(size_t)s0 * 128 + c0];
        unsigned u1 = *(const unsigned*)&h1[(size_t)s1 * 128 + c0];
        unsigned u2 = *(const unsigned*)&h1[(size_t)s2 * 128 + c0];
        unsigned u3 = *(const unsigned*)&h1[(size_t)s3 * 128 + c0];
        accx += q0 * lo16(u0) + q1 * lo16(u1) + q2 * lo16(u2) + q3 * lo16(u3);
        accy += q0 * hi16(u0) + q1 * hi16(u1) + q2 * hi16(u2) + q3 * hi16(u3);
        z += q0 + q1 + q2 + q3;
    }
    for (; j < end; ++j) {
        int s = csr[j];
        float q = p4[(size_t)j * 4 + hd];
        unsigned u = *(const unsigned*)&h1[(size_t)s * 128 + c0];
        accx += q * lo16(u);
        accy += q * hi16(u);
        z += q;
    }
    float invz = 1.0f / z;
    float vx = accx * invz + b1[c0];
    float vy = accy * invz + b1[c0 + 1];
    vx = vx > 0.f ? vx : __expf(vx) - 1.0f;   // ELU
    vy = vy > 0.f ? vy : __expf(vy) - 1.0f;
    __hip_bfloat162 o;
    o.x = __float2bfloat16(vx);
    o.y = __float2bfloat16(vy);
    *(__hip_bfloat162*)&out1[(size_t)d * 128 + c0] = o;
}

// ---------------- layer-2 aggregation + head mean + b2 + log_softmax, bf16 h ----------------

__global__ __launch_bounds__(256) void agg2_kernel(
        const __hip_bfloat16* __restrict__ h2, const float* __restrict__ p4,
        const int* __restrict__ rowptr, const int* __restrict__ csr,
        const float* __restrict__ b2, float* __restrict__ out) {
    int d = blockIdx.x * 4 + (threadIdx.x >> 6);
    if (d >= N_NODES) return;
    int lane = threadIdx.x & 63;
    bool active = lane < 40;
    int hd = lane / 10; if (hd > 3) hd = 3;
    float ax = 0.f, ay = 0.f, az = 0.f, aw = 0.f, z = 0.f;
    int beg = rowptr[d], end = rowptr[d + 1];
    int j = beg;
    for (; j + 3 < end; j += 4) {
        int s0 = csr[j], s1 = csr[j + 1], s2 = csr[j + 2], s3 = csr[j + 3];
        float q0 = p4[(size_t)(j + 0) * 4 + hd];
        float q1 = p4[(size_t)(j + 1) * 4 + hd];
        float q2 = p4[(size_t)(j + 2) * 4 + hd];
        float q3 = p4[(size_t)(j + 3) * 4 + hd];
        uint2 u0 = {0, 0}, u1 = {0, 0}, u2 = {0, 0}, u3 = {0, 0};
        if (active) {
            u0 = *(const uint2*)&h2[(size_t)s0 * 160 + lane * 4];
            u1 = *(const uint2*)&h2[(size_t)s1 * 160 + lane * 4];
            u2 = *(const uint2*)&h2[(size_t)s2 * 160 + lane * 4];
            u3 = *(const uint2*)&h2[(size_t)s3 * 160 + lane * 4];
        }
        ax += q0 * lo16(u0.x) + q1 * lo16(u1.x) + q2 * lo16(u2.x) + q3 * lo16(u3.x);
        ay += q0 * hi16(u0.x) + q1 * hi16(u1.x) + q2 * hi16(u2.x) + q3 * hi16(u3.x);
        az += q0 * lo16(u0.y) + q1 * lo16(u1.y) + q2 * lo16(u2.y) + q3 * lo16(u3.y);
        aw += q0 * hi16(u0.y) + q1 * hi16(u1.y) + q2 * hi16(u2.y) + q3 * hi16(u3.y);
        z += q0 + q1 + q2 + q3;
    }
    for (; j < end; ++j) {
        int s = csr[j];
        float q = p4[(size_t)j * 4 + hd];
        uint2 u = {0, 0};
        if (active) u = *(const uint2*)&h2[(size_t)s * 160 + lane * 4];
        ax += q * lo16(u.x);
        ay += q * hi16(u.x);
        az += q * lo16(u.y);
        aw += q * hi16(u.y);
        z += q;
    }
    float invz = 1.0f / z;
    float rx = ax * invz, ry = ay * invz, rz = az * invz, rw = aw * invz;
    float sx = rx + __shfl(rx, lane + 10) + __shfl(rx, lane + 20) + __shfl(rx, lane + 30);
    float sy = ry + __shfl(ry, lane + 10) + __shfl(ry, lane + 20) + __shfl(ry, lane + 30);
    float sz = rz + __shfl(rz, lane + 10) + __shfl(rz, lane + 20) + __shfl(rz, lane + 30);
    float sw = rw + __shfl(rw, lane + 10) + __shfl(rw, lane + 20) + __shfl(rw, lane + 30);
    int lc = lane < 10 ? lane : 9;
    float4 bb = *(const float4*)&b2[lc * 4];
    bool own = lane < 10;
    float vx = own ? sx * 0.25f + bb.x : -1e30f;
    float vy = own ? sy * 0.25f + bb.y : -1e30f;
    float vz = own ? sz * 0.25f + bb.z : -1e30f;
    float vw = own ? sw * 0.25f + bb.w : -1e30f;
    float m = fmaxf(fmaxf(vx, vy), fmaxf(vz, vw));
    #pragma unroll
    for (int off = 1; off < 16; off <<= 1) m = fmaxf(m, __shfl_xor(m, off));
    float ssum = 0.f;
    if (own) {
        ssum = __expf(vx - m) + __expf(vy - m) + __expf(vz - m) + __expf(vw - m);
    }
    #pragma unroll
    for (int off = 1; off < 16; off <<= 1) ssum += __shfl_xor(ssum, off);
    float lse = m + __logf(ssum);
    if (own) {
        float4 o = {vx - lse, vy - lse, vz - lse, vw - lse};
        *(float4*)&out[(size_t)d * 40 + lane * 4] = o;
    }
}

// ---------------- launch ----------------

extern "C" void kernel_launch(void* const* d_in, const int* in_sizes, int n_in,
                              void* d_out, int out_size, void* d_ws, size_t ws_size,
                              hipStream_t stream) {
    const float* x   = (const float*)d_in[0];
    const int*   ei  = (const int*)d_in[1];
    const float* W1  = (const float*)d_in[2];
    const float* as1 = (const float*)d_in[3];
    const float* ad1 = (const float*)d_in[4];
    const float* b1  = (const float*)d_in[5];
    const float* W2  = (const float*)d_in[6];
    const float* as2 = (const float*)d_in[7];
    const float* ad2 = (const float*)d_in[8];
    const float* b2  = (const float*)d_in[9];
    float* out = (float*)d_out;

    char* ws = (char*)d_ws;
    size_t off = 0;
    auto alloc = [&](size_t bytes) {
        void* p = ws + off;
        off += (bytes + 255) & ~(size_t)255;
        return p;
    };
    __hip_bfloat16* xb    = (__hip_bfloat16*)alloc((size_t)M_PAD * 128 * 2);
    __hip_bfloat16* h1b   = (__hip_bfloat16*)alloc((size_t)M_PAD * 128 * 2);
    __hip_bfloat16* out1b = (__hip_bfloat16*)alloc((size_t)M_PAD * 128 * 2);
    __hip_bfloat16* h2b   = (__hip_bfloat16*)alloc((size_t)M_PAD * 160 * 2);
    __hip_bfloat16* W1t   = (__hip_bfloat16*)alloc((size_t)128 * 128 * 2);
    __hip_bfloat16* W2t   = (__hip_bfloat16*)alloc((size_t)160 * 128 * 2);
    float* s_src1  = (float*)alloc((size_t)N_NODES * 4 * 4);
    float* s_dst1  = (float*)alloc((size_t)N_NODES * 4 * 4);
    float* s_src2  = (float*)alloc((size_t)N_NODES * 4 * 4);
    float* s_dst2  = (float*)alloc((size_t)N_NODES * 4 * 4);
    float* p4      = (float*)alloc((size_t)E_TOT * 4 * 4);
    int2*  tmp     = (int2*)alloc((size_t)E_TOT * 8);
    int*   rowptr  = (int*)alloc((size_t)(N_NODES + 1) * 4);
    int*   csr     = (int*)alloc((size_t)E_TOT * 4);
    int*   csrd    = (int*)alloc((size_t)E_TOT * 4);
    int*   cnt     = (int*)alloc((size_t)REP * BUCKETS * 4);
    int*   cur     = (int*)alloc((size_t)REP * BUCKETS * 4);
    int*   bsum    = (int*)alloc((size_t)BUCKETS * 4);
    int*   boff    = (int*)alloc((size_t)(BUCKETS + 1) * 4);

    // CSR build (sliced counting-sort partition; no high-contention atomics)
    slice_count_kernel<<<REP, 256, 0, stream>>>(ei, cnt);
    col_scan_kernel<<<BUCKETS, REP, 0, stream>>>(cnt, bsum);
    bucket_scan_kernel<<<1, 1024, 0, stream>>>(bsum, boff);
    cursor_init_kernel<<<(REP * BUCKETS + 255) / 256, 256, 0, stream>>>(cnt, boff, cur);
    bucket_scatter_kernel<<<REP, 256, 0, stream>>>(ei, cur, tmp);
    bucket_build_kernel<<<BUCKETS, 256, 0, stream>>>(tmp, boff, rowptr, csr, csrd);

    // dtype prep
    cvt_x_kernel<<<(N_NODES * 32 + 255) / 256, 256, 0, stream>>>(x, xb, N_NODES * 32);
    cvt_wt_kernel<<<(128 * 128 + 255) / 256, 256, 0, stream>>>(W1, W1t, 128, 128);
    cvt_wt_kernel<<<(128 * 160 + 255) / 256, 256, 0, stream>>>(W2, W2t, 128, 160);

    // layer 1
    mfma_gemm_kernel<128><<<M_PAD / 128, 256, 0, stream>>>(xb, W1t, h1b);
    score_kernel<32, 128><<<(N_NODES * 4 + 255) / 256, 256, 0, stream>>>(h1b, as1, ad1, s_src1, s_dst1, N_NODES);
    edge_p_kernel<<<(E_TOT + 255) / 256, 256, 0, stream>>>(csr, csrd, s_src1, s_dst1, p4, E_TOT);
    agg1_kernel<<<(N_NODES + 3) / 4, 256, 0, stream>>>(h1b, p4, rowptr, csr, b1, out1b);

    // layer 2
    mfma_gemm_kernel<160><<<M_PAD / 128, 256, 0, stream>>>(out1b, W2t, h2b);
    score_kernel<40, 160><<<(N_NODES * 4 + 255) / 256, 256, 0, stream>>>(h2b, as2, ad2, s_src2, s_dst2, N_NODES);
    edge_p_kernel<<<(E_TOT + 255) / 256, 256, 0, stream>>>(csr, csrd, s_src2, s_dst2, p4, E_TOT);
    agg2_kernel<<<(N_NODES + 3) / 4, 256, 0, stream>>>(h2b, p4, rowptr, csr, b2, out);
}

// Round 6
// 376.595 us; speedup vs baseline: 2.0634x; 1.2099x over previous
//
#include <hip/hip_runtime.h>
#include <hip/hip_bf16.h>

#define N_NODES 100000
#define M_PAD   100096            // 782 * 128, padded row count for MFMA GEMM
#define N_EDGES 1600000
#define E_TOT   (N_EDGES + N_NODES)   // + self loops
#define NEG_SLOPE 0.2f

#define G_NODES 128                                  // nodes per bucket (pow2)
#define BUCKETS ((N_NODES + G_NODES - 1) / G_NODES)  // 782
#define REP 512                                      // slices (one block each)
#define SLICE ((E_TOT + REP - 1) / REP)              // 3321 edges per slice

typedef __attribute__((ext_vector_type(8))) short s16x8;
typedef __attribute__((ext_vector_type(4))) float f32x4;

__device__ __forceinline__ float lo16(unsigned u) { return __uint_as_float(u << 16); }
__device__ __forceinline__ float hi16(unsigned u) { return __uint_as_float(u & 0xffff0000u); }

// ---------------- CSR build: sliced counting-sort partition ----------------

// per-slice histogram of dst buckets (LDS atomics only; plain global stores)
__global__ __launch_bounds__(256) void slice_count_kernel(const int* __restrict__ ei,
                                                          int* __restrict__ cnt) {
    __shared__ int h[BUCKETS];
    for (int i = threadIdx.x; i < BUCKETS; i += 256) h[i] = 0;
    __syncthreads();
    int r = blockIdx.x;
    int lo = r * SLICE, hi = min(lo + SLICE, E_TOT);
    for (int e = lo + threadIdx.x; e < hi; e += 256) {
        int d = (e < N_EDGES) ? ei[N_EDGES + e] : e - N_EDGES;
        atomicAdd(&h[d >> 7], 1);
    }
    __syncthreads();
    for (int i = threadIdx.x; i < BUCKETS; i += 256)
        cnt[(size_t)r * BUCKETS + i] = h[i];
}

// exclusive scan down each bucket's column of slice counts (block = bucket)
__global__ __launch_bounds__(REP) void col_scan_kernel(int* __restrict__ cnt,
                                                       int* __restrict__ bsum) {
    __shared__ int lds[REP];
    int b = blockIdx.x, tid = threadIdx.x;
    int v = cnt[(size_t)tid * BUCKETS + b];
    lds[tid] = v;
    __syncthreads();
    for (int off = 1; off < REP; off <<= 1) {
        int t = (tid >= off) ? lds[tid - off] : 0;
        __syncthreads();
        lds[tid] += t;
        __syncthreads();
    }
    cnt[(size_t)tid * BUCKETS + b] = lds[tid] - v;   // exclusive within column
    if (tid == REP - 1) bsum[b] = lds[tid];
}

// scan of bucket totals (single block)
__global__ __launch_bounds__(1024) void bucket_scan_kernel(const int* __restrict__ bsum,
                                                           int* __restrict__ boff) {
    __shared__ int lds[1024];
    int tid = threadIdx.x;
    int v = (tid < BUCKETS) ? bsum[tid] : 0;
    lds[tid] = v;
    __syncthreads();
    for (int off = 1; off < 1024; off <<= 1) {
        int t = (tid >= off) ? lds[tid - off] : 0;
        __syncthreads();
        lds[tid] += t;
        __syncthreads();
    }
    if (tid < BUCKETS) boff[tid] = lds[tid] - v;
    if (tid == 0) boff[BUCKETS] = E_TOT;
}

// scatter (s,d) into bucket-contiguous tmp; cursors live in LDS (no global atomics)
__global__ __launch_bounds__(256) void bucket_scatter_kernel(const int* __restrict__ ei,
                                                             const int* __restrict__ colx,
                                                             const int* __restrict__ boff,
                                                             int2* __restrict__ tmp) {
    __shared__ int lcur[BUCKETS];
    int r = blockIdx.x;
    for (int i = threadIdx.x; i < BUCKETS; i += 256)
        lcur[i] = boff[i] + colx[(size_t)r * BUCKETS + i];
    __syncthreads();
    int lo = r * SLICE, hi = min(lo + SLICE, E_TOT);
    for (int e = lo + threadIdx.x; e < hi; e += 256) {
        int s, d;
        if (e < N_EDGES) { s = ei[e]; d = ei[N_EDGES + e]; }
        else             { s = d = e - N_EDGES; }
        int pos = atomicAdd(&lcur[d >> 7], 1);
        tmp[pos] = make_int2(s, d);
    }
}

// per-bucket local count + scan -> rowptr; then place csr/csrd (L2-resident region)
__global__ __launch_bounds__(256) void bucket_build_kernel(const int2* __restrict__ tmp,
                                                           const int* __restrict__ boff,
                                                           int* __restrict__ rowptr,
                                                           int* __restrict__ csr,
                                                           int* __restrict__ csrd) {
    __shared__ int hcnt[G_NODES];
    __shared__ int hoff[G_NODES];
    int b = blockIdx.x;
    int base = boff[b], cnt = boff[b + 1] - base;
    int tid = threadIdx.x;
    if (tid < G_NODES) hcnt[tid] = 0;
    __syncthreads();
    for (int i = tid; i < cnt; i += 256)
        atomicAdd(&hcnt[tmp[base + i].y & (G_NODES - 1)], 1);
    __syncthreads();
    if (tid < G_NODES) hoff[tid] = hcnt[tid];
    __syncthreads();
    for (int off = 1; off < G_NODES; off <<= 1) {
        int t = (tid < G_NODES && tid >= off) ? hoff[tid - off] : 0;
        __syncthreads();
        if (tid < G_NODES) hoff[tid] += t;
        __syncthreads();
    }
    if (tid < G_NODES) {
        int excl = hoff[tid] - hcnt[tid];
        int node = b * G_NODES + tid;
        if (node < N_NODES) rowptr[node] = base + excl;
        hcnt[tid] = excl;       // reuse as cursor
    }
    __syncthreads();
    for (int i = tid; i < cnt; i += 256) {
        int2 e = tmp[base + i];
        int pos = base + atomicAdd(&hcnt[e.y & (G_NODES - 1)], 1);
        csr[pos] = e.x;
        csrd[pos] = e.y;
    }
    if (b == 0 && tid == 0) rowptr[N_NODES] = E_TOT;
}

// ---------------- dtype conversion ----------------

__global__ void cvt_x_kernel(const float* __restrict__ in, __hip_bfloat16* __restrict__ out, int n4) {
    int i = blockIdx.x * blockDim.x + threadIdx.x;
    if (i >= n4) return;
    float4 v = ((const float4*)in)[i];
    __hip_bfloat162 a, b;
    a.x = __float2bfloat16(v.x); a.y = __float2bfloat16(v.y);
    b.x = __float2bfloat16(v.z); b.y = __float2bfloat16(v.w);
    *(__hip_bfloat162*)&out[(size_t)i * 4]     = a;
    *(__hip_bfloat162*)&out[(size_t)i * 4 + 2] = b;
}

// W [K][Nc] f32 -> Wt [Nc][K] bf16
__global__ void cvt_wt_kernel(const float* __restrict__ W, __hip_bfloat16* __restrict__ Wt, int K, int Nc) {
    int idx = blockIdx.x * blockDim.x + threadIdx.x;
    if (idx >= K * Nc) return;
    int k = idx / Nc, n = idx - k * Nc;
    Wt[n * K + k] = __float2bfloat16(W[idx]);
}

// ---------------- MFMA GEMM: C[m, :] = A[m, :] @ Bt^T, K = 128 ----------------

template<int NCOLS>
__global__ __launch_bounds__(256) void mfma_gemm_kernel(const __hip_bfloat16* __restrict__ A,
                                                        const __hip_bfloat16* __restrict__ Bt,
                                                        __hip_bfloat16* __restrict__ C) {
    constexpr int CG = NCOLS / 32;           // 16-col groups per wave
    int wid = threadIdx.x >> 6;
    int lane = threadIdx.x & 63;
    int wr = wid >> 1, wc = wid & 1;
    int l15 = lane & 15, lk = lane >> 4;     // lk in 0..3

    s16x8 bfrag[CG][4];
    #pragma unroll
    for (int cg = 0; cg < CG; ++cg) {
        int col = wc * (NCOLS / 2) + cg * 16 + l15;
        #pragma unroll
        for (int ks = 0; ks < 4; ++ks)
            bfrag[cg][ks] = *(const s16x8*)&Bt[col * 128 + ks * 32 + lk * 8];
    }
    int rowblk = blockIdx.x * 128;
    #pragma unroll
    for (int st = 0; st < 4; ++st) {
        int rbase = rowblk + st * 32 + wr * 16;
        s16x8 afrag[4];
        #pragma unroll
        for (int ks = 0; ks < 4; ++ks)
            afrag[ks] = *(const s16x8*)&A[(size_t)(rbase + l15) * 128 + ks * 32 + lk * 8];
        f32x4 acc[CG];
        #pragma unroll
        for (int cg = 0; cg < CG; ++cg) acc[cg] = (f32x4){0.f, 0.f, 0.f, 0.f};
        #pragma unroll
        for (int ks = 0; ks < 4; ++ks) {
            #pragma unroll
            for (int cg = 0; cg < CG; ++cg)
                acc[cg] = __builtin_amdgcn_mfma_f32_16x16x32_bf16(afrag[ks], bfrag[cg][ks], acc[cg], 0, 0, 0);
        }
        #pragma unroll
        for (int cg = 0; cg < CG; ++cg) {
            int c = wc * (NCOLS / 2) + cg * 16 + l15;
            #pragma unroll
            for (int j = 0; j < 4; ++j)
                C[(size_t)(rbase + lk * 4 + j) * NCOLS + c] = __float2bfloat16(acc[cg][j]);
        }
    }
}

// ---------------- attention scores: s[n,h] = <h[n,h,:], att[h,:]> ----------------

template<int C, int J>
__global__ void score_kernel(const __hip_bfloat16* __restrict__ h, const float* __restrict__ att_src,
                             const float* __restrict__ att_dst,
                             float* __restrict__ s_src, float* __restrict__ s_dst, int n) {
    int idx = blockIdx.x * blockDim.x + threadIdx.x;   // node*4 + head
    if (idx >= n * 4) return;
    int node = idx >> 2, hd = idx & 3;
    const __hip_bfloat16* hp = h + (size_t)node * J + hd * C;
    const float* as = att_src + hd * C;
    const float* ad = att_dst + hd * C;
    float ss = 0.f, sd = 0.f;
    #pragma unroll
    for (int c8 = 0; c8 < C / 8; ++c8) {
        uint4 u = *(const uint4*)&hp[c8 * 8];   // 8 bf16
        const unsigned* uw = (const unsigned*)&u;
        #pragma unroll
        for (int t = 0; t < 4; ++t) {
            int c = c8 * 8 + t * 2;
            float v0 = lo16(uw[t]);
            float v1 = hi16(uw[t]);
            ss += v0 * as[c] + v1 * as[c + 1];
            sd += v0 * ad[c] + v1 * ad[c + 1];
        }
    }
    s_src[idx] = ss;
    s_dst[idx] = sd;
}

// ---------------- per-edge unnormalized softmax weights (CSR order) ----------------

__global__ void edge_p_kernel(const int* __restrict__ csr, const int* __restrict__ csrd,
                              const float* __restrict__ s_src, const float* __restrict__ s_dst,
                              float* __restrict__ p4, int etot) {
    int j = blockIdx.x * blockDim.x + threadIdx.x;
    if (j >= etot) return;
    int s = csr[j], d = csrd[j];
    float4 a = *(const float4*)&s_src[(size_t)s * 4];
    float4 b = *(const float4*)&s_dst[(size_t)d * 4];
    float4 r;
    float e;
    e = a.x + b.x; e = e > 0.f ? e : NEG_SLOPE * e; r.x = __expf(e);
    e = a.y + b.y; e = e > 0.f ? e : NEG_SLOPE * e; r.y = __expf(e);
    e = a.z + b.z; e = e > 0.f ? e : NEG_SLOPE * e; r.z = __expf(e);
    e = a.w + b.w; e = e > 0.f ? e : NEG_SLOPE * e; r.w = __expf(e);
    *(float4*)&p4[(size_t)j * 4] = r;
}

// ---------------- layer-1 aggregation (+bias +ELU), bf16 h, unroll x8 ----------------

__global__ __launch_bounds__(256) void agg1_kernel(
        const __hip_bfloat16* __restrict__ h1, const float* __restrict__ p4,
        const int* __restrict__ rowptr, const int* __restrict__ csr,
        const float* __restrict__ b1, __hip_bfloat16* __restrict__ out1) {
    int d = blockIdx.x * 4 + (threadIdx.x >> 6);
    if (d >= N_NODES) return;
    int lane = threadIdx.x & 63;
    int c0 = lane * 2;
    int hd = lane >> 4;
    float accx = 0.f, accy = 0.f, z = 0.f;
    int beg = rowptr[d], end = rowptr[d + 1];
    int j = beg;
    for (; j + 7 < end; j += 8) {
        int sv[8]; float qv[8]; unsigned uv[8];
        #pragma unroll
        for (int t = 0; t < 8; ++t) sv[t] = csr[j + t];
        #pragma unroll
        for (int t = 0; t < 8; ++t) qv[t] = p4[(size_t)(j + t) * 4 + hd];
        #pragma unroll
        for (int t = 0; t < 8; ++t) uv[t] = *(const unsigned*)&h1[(size_t)sv[t] * 128 + c0];
        #pragma unroll
        for (int t = 0; t < 8; ++t) {
            accx += qv[t] * lo16(uv[t]);
            accy += qv[t] * hi16(uv[t]);
            z += qv[t];
        }
    }
    for (; j < end; ++j) {
        int s = csr[j];
        float q = p4[(size_t)j * 4 + hd];
        unsigned u = *(const unsigned*)&h1[(size_t)s * 128 + c0];
        accx += q * lo16(u);
        accy += q * hi16(u);
        z += q;
    }
    float invz = 1.0f / z;
    float vx = accx * invz + b1[c0];
    float vy = accy * invz + b1[c0 + 1];
    vx = vx > 0.f ? vx : __expf(vx) - 1.0f;   // ELU
    vy = vy > 0.f ? vy : __expf(vy) - 1.0f;
    __hip_bfloat162 o;
    o.x = __float2bfloat16(vx);
    o.y = __float2bfloat16(vy);
    *(__hip_bfloat162*)&out1[(size_t)d * 128 + c0] = o;
}

// ---------------- layer-2 aggregation + head mean + b2 + log_softmax, bf16 h, unroll x8 ----------------

__global__ __launch_bounds__(256) void agg2_kernel(
        const __hip_bfloat16* __restrict__ h2, const float* __restrict__ p4,
        const int* __restrict__ rowptr, const int* __restrict__ csr,
        const float* __restrict__ b2, float* __restrict__ out) {
    int d = blockIdx.x * 4 + (threadIdx.x >> 6);
    if (d >= N_NODES) return;
    int lane = threadIdx.x & 63;
    bool active = lane < 40;
    int hd = lane / 10; if (hd > 3) hd = 3;
    float ax = 0.f, ay = 0.f, az = 0.f, aw = 0.f, z = 0.f;
    int beg = rowptr[d], end = rowptr[d + 1];
    int j = beg;
    for (; j + 7 < end; j += 8) {
        int sv[8]; float qv[8]; uint2 uv[8];
        #pragma unroll
        for (int t = 0; t < 8; ++t) sv[t] = csr[j + t];
        #pragma unroll
        for (int t = 0; t < 8; ++t) qv[t] = p4[(size_t)(j + t) * 4 + hd];
        #pragma unroll
        for (int t = 0; t < 8; ++t)
            uv[t] = active ? *(const uint2*)&h2[(size_t)sv[t] * 160 + lane * 4] : make_uint2(0, 0);
        #pragma unroll
        for (int t = 0; t < 8; ++t) {
            ax += qv[t] * lo16(uv[t].x);
            ay += qv[t] * hi16(uv[t].x);
            az += qv[t] * lo16(uv[t].y);
            aw += qv[t] * hi16(uv[t].y);
            z += qv[t];
        }
    }
    for (; j < end; ++j) {
        int s = csr[j];
        float q = p4[(size_t)j * 4 + hd];
        uint2 u = {0, 0};
        if (active) u = *(const uint2*)&h2[(size_t)s * 160 + lane * 4];
        ax += q * lo16(u.x);
        ay += q * hi16(u.x);
        az += q * lo16(u.y);
        aw += q * hi16(u.y);
        z += q;
    }
    float invz = 1.0f / z;
    float rx = ax * invz, ry = ay * invz, rz = az * invz, rw = aw * invz;
    float sx = rx + __shfl(rx, lane + 10) + __shfl(rx, lane + 20) + __shfl(rx, lane + 30);
    float sy = ry + __shfl(ry, lane + 10) + __shfl(ry, lane + 20) + __shfl(ry, lane + 30);
    float sz = rz + __shfl(rz, lane + 10) + __shfl(rz, lane + 20) + __shfl(rz, lane + 30);
    float sw = rw + __shfl(rw, lane + 10) + __shfl(rw, lane + 20) + __shfl(rw, lane + 30);
    int lc = lane < 10 ? lane : 9;
    float4 bb = *(const float4*)&b2[lc * 4];
    bool own = lane < 10;
    float vx = own ? sx * 0.25f + bb.x : -1e30f;
    float vy = own ? sy * 0.25f + bb.y : -1e30f;
    float vz = own ? sz * 0.25f + bb.z : -1e30f;
    float vw = own ? sw * 0.25f + bb.w : -1e30f;
    float m = fmaxf(fmaxf(vx, vy), fmaxf(vz, vw));
    #pragma unroll
    for (int off = 1; off < 16; off <<= 1) m = fmaxf(m, __shfl_xor(m, off));
    float ssum = 0.f;
    if (own) {
        ssum = __expf(vx - m) + __expf(vy - m) + __expf(vz - m) + __expf(vw - m);
    }
    #pragma unroll
    for (int off = 1; off < 16; off <<= 1) ssum += __shfl_xor(ssum, off);
    float lse = m + __logf(ssum);
    if (own) {
        float4 o = {vx - lse, vy - lse, vz - lse, vw - lse};
        *(float4*)&out[(size_t)d * 40 + lane * 4] = o;
    }
}

// ---------------- launch ----------------

extern "C" void kernel_launch(void* const* d_in, const int* in_sizes, int n_in,
                              void* d_out, int out_size, void* d_ws, size_t ws_size,
                              hipStream_t stream) {
    const float* x   = (const float*)d_in[0];
    const int*   ei  = (const int*)d_in[1];
    const float* W1  = (const float*)d_in[2];
    const float* as1 = (const float*)d_in[3];
    const float* ad1 = (const float*)d_in[4];
    const float* b1  = (const float*)d_in[5];
    const float* W2  = (const float*)d_in[6];
    const float* as2 = (const float*)d_in[7];
    const float* ad2 = (const float*)d_in[8];
    const float* b2  = (const float*)d_in[9];
    float* out = (float*)d_out;

    char* ws = (char*)d_ws;
    size_t off = 0;
    auto alloc = [&](size_t bytes) {
        void* p = ws + off;
        off += (bytes + 255) & ~(size_t)255;
        return p;
    };
    __hip_bfloat16* xb    = (__hip_bfloat16*)alloc((size_t)M_PAD * 128 * 2);
    __hip_bfloat16* h1b   = (__hip_bfloat16*)alloc((size_t)M_PAD * 128 * 2);
    __hip_bfloat16* out1b = (__hip_bfloat16*)alloc((size_t)M_PAD * 128 * 2);
    __hip_bfloat16* h2b   = (__hip_bfloat16*)alloc((size_t)M_PAD * 160 * 2);
    __hip_bfloat16* W1t   = (__hip_bfloat16*)alloc((size_t)128 * 128 * 2);
    __hip_bfloat16* W2t   = (__hip_bfloat16*)alloc((size_t)160 * 128 * 2);
    float* s_src1  = (float*)alloc((size_t)N_NODES * 4 * 4);
    float* s_dst1  = (float*)alloc((size_t)N_NODES * 4 * 4);
    float* s_src2  = (float*)alloc((size_t)N_NODES * 4 * 4);
    float* s_dst2  = (float*)alloc((size_t)N_NODES * 4 * 4);
    float* p4      = (float*)alloc((size_t)E_TOT * 4 * 4);
    int2*  tmp     = (int2*)alloc((size_t)E_TOT * 8);
    int*   rowptr  = (int*)alloc((size_t)(N_NODES + 1) * 4);
    int*   csr     = (int*)alloc((size_t)E_TOT * 4);
    int*   csrd    = (int*)alloc((size_t)E_TOT * 4);
    int*   cnt     = (int*)alloc((size_t)REP * BUCKETS * 4);
    int*   bsum    = (int*)alloc((size_t)BUCKETS * 4);
    int*   boff    = (int*)alloc((size_t)(BUCKETS + 1) * 4);

    // CSR build (sliced counting-sort partition; LDS cursors, no global atomics)
    slice_count_kernel<<<REP, 256, 0, stream>>>(ei, cnt);
    col_scan_kernel<<<BUCKETS, REP, 0, stream>>>(cnt, bsum);
    bucket_scan_kernel<<<1, 1024, 0, stream>>>(bsum, boff);
    bucket_scatter_kernel<<<REP, 256, 0, stream>>>(ei, cnt, boff, tmp);
    bucket_build_kernel<<<BUCKETS, 256, 0, stream>>>(tmp, boff, rowptr, csr, csrd);

    // dtype prep
    cvt_x_kernel<<<(N_NODES * 32 + 255) / 256, 256, 0, stream>>>(x, xb, N_NODES * 32);
    cvt_wt_kernel<<<(128 * 128 + 255) / 256, 256, 0, stream>>>(W1, W1t, 128, 128);
    cvt_wt_kernel<<<(128 * 160 + 255) / 256, 256, 0, stream>>>(W2, W2t, 128, 160);

    // layer 1
    mfma_gemm_kernel<128><<<M_PAD / 128, 256, 0, stream>>>(xb, W1t, h1b);
    score_kernel<32, 128><<<(N_NODES * 4 + 255) / 256, 256, 0, stream>>>(h1b, as1, ad1, s_src1, s_dst1, N_NODES);
    edge_p_kernel<<<(E_TOT + 255) / 256, 256, 0, stream>>>(csr, csrd, s_src1, s_dst1, p4, E_TOT);
    agg1_kernel<<<(N_NODES + 3) / 4, 256, 0, stream>>>(h1b, p4, rowptr, csr, b1, out1b);

    // layer 2
    mfma_gemm_kernel<160><<<M_PAD / 128, 256, 0, stream>>>(out1b, W2t, h2b);
    score_kernel<40, 160><<<(N_NODES * 4 + 255) / 256, 256, 0, stream>>>(h2b, as2, ad2, s_src2, s_dst2, N_NODES);
    edge_p_kernel<<<(E_TOT + 255) / 256, 256, 0, stream>>>(csr, csrd, s_src2, s_dst2, p4, E_TOT);
    agg2_kernel<<<(N_NODES + 3) / 4, 256, 0, stream>>>(h2b, p4, rowptr, csr, b2, out);
}

// Round 7
// 324.174 us; speedup vs baseline: 2.3971x; 1.1617x over previous
//
#include <hip/hip_runtime.h>
#include <hip/hip_bf16.h>

#define N_NODES 100000
#define M_PAD   100096            // 782 * 128, padded row count for MFMA GEMM
#define N_EDGES 1600000
#define E_TOT   (N_EDGES + N_NODES)   // + self loops
#define NEG_SLOPE 0.2f

#define G_NODES 128                                  // nodes per bucket (pow2)
#define BUCKETS ((N_NODES + G_NODES - 1) / G_NODES)  // 782
#define REP 512                                      // slices (one block each)
#define SLICE ((E_TOT + REP - 1) / REP)              // 3321 edges per slice

typedef __attribute__((ext_vector_type(8))) short s16x8;
typedef __attribute__((ext_vector_type(4))) float f32x4;

__device__ __forceinline__ float lo16(unsigned u) { return __uint_as_float(u << 16); }
__device__ __forceinline__ float hi16(unsigned u) { return __uint_as_float(u & 0xffff0000u); }

__device__ __forceinline__ short f2bf(float f) {
    __hip_bfloat16 b = __float2bfloat16(f);
    return *(short*)&b;
}

// ---------------- CSR build: sliced counting-sort partition ----------------

// per-slice histogram of dst buckets (LDS atomics only; plain global stores)
__global__ __launch_bounds__(256) void slice_count_kernel(const int* __restrict__ ei,
                                                          int* __restrict__ cnt) {
    __shared__ int h[BUCKETS];
    for (int i = threadIdx.x; i < BUCKETS; i += 256) h[i] = 0;
    __syncthreads();
    int r = blockIdx.x;
    int lo = r * SLICE, hi = min(lo + SLICE, E_TOT);
    for (int e = lo + threadIdx.x; e < hi; e += 256) {
        int d = (e < N_EDGES) ? ei[N_EDGES + e] : e - N_EDGES;
        atomicAdd(&h[d >> 7], 1);
    }
    __syncthreads();
    for (int i = threadIdx.x; i < BUCKETS; i += 256)
        cnt[(size_t)r * BUCKETS + i] = h[i];
}

// exclusive scan down each bucket's column of slice counts (block = bucket)
__global__ __launch_bounds__(REP) void col_scan_kernel(int* __restrict__ cnt,
                                                       int* __restrict__ bsum) {
    __shared__ int lds[REP];
    int b = blockIdx.x, tid = threadIdx.x;
    int v = cnt[(size_t)tid * BUCKETS + b];
    lds[tid] = v;
    __syncthreads();
    for (int off = 1; off < REP; off <<= 1) {
        int t = (tid >= off) ? lds[tid - off] : 0;
        __syncthreads();
        lds[tid] += t;
        __syncthreads();
    }
    cnt[(size_t)tid * BUCKETS + b] = lds[tid] - v;   // exclusive within column
    if (tid == REP - 1) bsum[b] = lds[tid];
}

// scan of bucket totals (single block)
__global__ __launch_bounds__(1024) void bucket_scan_kernel(const int* __restrict__ bsum,
                                                           int* __restrict__ boff) {
    __shared__ int lds[1024];
    int tid = threadIdx.x;
    int v = (tid < BUCKETS) ? bsum[tid] : 0;
    lds[tid] = v;
    __syncthreads();
    for (int off = 1; off < 1024; off <<= 1) {
        int t = (tid >= off) ? lds[tid - off] : 0;
        __syncthreads();
        lds[tid] += t;
        __syncthreads();
    }
    if (tid < BUCKETS) boff[tid] = lds[tid] - v;
    if (tid == 0) boff[BUCKETS] = E_TOT;
}

// scatter (s,d) into bucket-contiguous tmp; cursors live in LDS (no global atomics)
__global__ __launch_bounds__(256) void bucket_scatter_kernel(const int* __restrict__ ei,
                                                             const int* __restrict__ colx,
                                                             const int* __restrict__ boff,
                                                             int2* __restrict__ tmp) {
    __shared__ int lcur[BUCKETS];
    int r = blockIdx.x;
    for (int i = threadIdx.x; i < BUCKETS; i += 256)
        lcur[i] = boff[i] + colx[(size_t)r * BUCKETS + i];
    __syncthreads();
    int lo = r * SLICE, hi = min(lo + SLICE, E_TOT);
    for (int e = lo + threadIdx.x; e < hi; e += 256) {
        int s, d;
        if (e < N_EDGES) { s = ei[e]; d = ei[N_EDGES + e]; }
        else             { s = d = e - N_EDGES; }
        int pos = atomicAdd(&lcur[d >> 7], 1);
        tmp[pos] = make_int2(s, d);
    }
}

// per-bucket local count + scan -> rowptr; then place csr/csrd (L2-resident region)
__global__ __launch_bounds__(256) void bucket_build_kernel(const int2* __restrict__ tmp,
                                                           const int* __restrict__ boff,
                                                           int* __restrict__ rowptr,
                                                           int* __restrict__ csr,
                                                           int* __restrict__ csrd) {
    __shared__ int hcnt[G_NODES];
    __shared__ int hoff[G_NODES];
    int b = blockIdx.x;
    int base = boff[b], cnt = boff[b + 1] - base;
    int tid = threadIdx.x;
    if (tid < G_NODES) hcnt[tid] = 0;
    __syncthreads();
    for (int i = tid; i < cnt; i += 256)
        atomicAdd(&hcnt[tmp[base + i].y & (G_NODES - 1)], 1);
    __syncthreads();
    if (tid < G_NODES) hoff[tid] = hcnt[tid];
    __syncthreads();
    for (int off = 1; off < G_NODES; off <<= 1) {
        int t = (tid < G_NODES && tid >= off) ? hoff[tid - off] : 0;
        __syncthreads();
        if (tid < G_NODES) hoff[tid] += t;
        __syncthreads();
    }
    if (tid < G_NODES) {
        int excl = hoff[tid] - hcnt[tid];
        int node = b * G_NODES + tid;
        if (node < N_NODES) rowptr[node] = base + excl;
        hcnt[tid] = excl;       // reuse as cursor
    }
    __syncthreads();
    for (int i = tid; i < cnt; i += 256) {
        int2 e = tmp[base + i];
        int pos = base + atomicAdd(&hcnt[e.y & (G_NODES - 1)], 1);
        csr[pos] = e.x;
        csrd[pos] = e.y;
    }
    if (b == 0 && tid == 0) rowptr[N_NODES] = E_TOT;
}

// ---------------- dtype conversion ----------------

// W [K][Nc] f32 -> Wt [Nc][K] bf16
__global__ void cvt_wt_kernel(const float* __restrict__ W, __hip_bfloat16* __restrict__ Wt, int K, int Nc) {
    int idx = blockIdx.x * blockDim.x + threadIdx.x;
    if (idx >= K * Nc) return;
    int k = idx / Nc, n = idx - k * Nc;
    Wt[n * K + k] = __float2bfloat16(W[idx]);
}

// ---------------- MFMA GEMM (layer 1): A is f32, converted in-register ----------------

template<int NCOLS>
__global__ __launch_bounds__(256) void mfma_gemm_f32a_kernel(const float* __restrict__ A,
                                                             const __hip_bfloat16* __restrict__ Bt,
                                                             __hip_bfloat16* __restrict__ C) {
    constexpr int CG = NCOLS / 32;
    int wid = threadIdx.x >> 6;
    int lane = threadIdx.x & 63;
    int wr = wid >> 1, wc = wid & 1;
    int l15 = lane & 15, lk = lane >> 4;

    s16x8 bfrag[CG][4];
    #pragma unroll
    for (int cg = 0; cg < CG; ++cg) {
        int col = wc * (NCOLS / 2) + cg * 16 + l15;
        #pragma unroll
        for (int ks = 0; ks < 4; ++ks)
            bfrag[cg][ks] = *(const s16x8*)&Bt[col * 128 + ks * 32 + lk * 8];
    }
    int rowblk = blockIdx.x * 128;
    #pragma unroll
    for (int st = 0; st < 4; ++st) {
        int rbase = rowblk + st * 32 + wr * 16;
        int row = rbase + l15;
        bool ok = row < N_NODES;
        s16x8 afrag[4];
        #pragma unroll
        for (int ks = 0; ks < 4; ++ks) {
            if (ok) {
                float4 a0 = *(const float4*)&A[(size_t)row * 128 + ks * 32 + lk * 8];
                float4 a1 = *(const float4*)&A[(size_t)row * 128 + ks * 32 + lk * 8 + 4];
                s16x8 af;
                af[0] = f2bf(a0.x); af[1] = f2bf(a0.y); af[2] = f2bf(a0.z); af[3] = f2bf(a0.w);
                af[4] = f2bf(a1.x); af[5] = f2bf(a1.y); af[6] = f2bf(a1.z); af[7] = f2bf(a1.w);
                afrag[ks] = af;
            } else {
                afrag[ks] = (s16x8){0,0,0,0,0,0,0,0};
            }
        }
        f32x4 acc[CG];
        #pragma unroll
        for (int cg = 0; cg < CG; ++cg) acc[cg] = (f32x4){0.f, 0.f, 0.f, 0.f};
        #pragma unroll
        for (int ks = 0; ks < 4; ++ks) {
            #pragma unroll
            for (int cg = 0; cg < CG; ++cg)
                acc[cg] = __builtin_amdgcn_mfma_f32_16x16x32_bf16(afrag[ks], bfrag[cg][ks], acc[cg], 0, 0, 0);
        }
        #pragma unroll
        for (int cg = 0; cg < CG; ++cg) {
            int c = wc * (NCOLS / 2) + cg * 16 + l15;
            #pragma unroll
            for (int j = 0; j < 4; ++j)
                C[(size_t)(rbase + lk * 4 + j) * NCOLS + c] = __float2bfloat16(acc[cg][j]);
        }
    }
}

// ---------------- MFMA GEMM (layer 2): bf16 A ----------------

template<int NCOLS>
__global__ __launch_bounds__(256) void mfma_gemm_kernel(const __hip_bfloat16* __restrict__ A,
                                                        const __hip_bfloat16* __restrict__ Bt,
                                                        __hip_bfloat16* __restrict__ C) {
    constexpr int CG = NCOLS / 32;
    int wid = threadIdx.x >> 6;
    int lane = threadIdx.x & 63;
    int wr = wid >> 1, wc = wid & 1;
    int l15 = lane & 15, lk = lane >> 4;

    s16x8 bfrag[CG][4];
    #pragma unroll
    for (int cg = 0; cg < CG; ++cg) {
        int col = wc * (NCOLS / 2) + cg * 16 + l15;
        #pragma unroll
        for (int ks = 0; ks < 4; ++ks)
            bfrag[cg][ks] = *(const s16x8*)&Bt[col * 128 + ks * 32 + lk * 8];
    }
    int rowblk = blockIdx.x * 128;
    #pragma unroll
    for (int st = 0; st < 4; ++st) {
        int rbase = rowblk + st * 32 + wr * 16;
        s16x8 afrag[4];
        #pragma unroll
        for (int ks = 0; ks < 4; ++ks)
            afrag[ks] = *(const s16x8*)&A[(size_t)(rbase + l15) * 128 + ks * 32 + lk * 8];
        f32x4 acc[CG];
        #pragma unroll
        for (int cg = 0; cg < CG; ++cg) acc[cg] = (f32x4){0.f, 0.f, 0.f, 0.f};
        #pragma unroll
        for (int ks = 0; ks < 4; ++ks) {
            #pragma unroll
            for (int cg = 0; cg < CG; ++cg)
                acc[cg] = __builtin_amdgcn_mfma_f32_16x16x32_bf16(afrag[ks], bfrag[cg][ks], acc[cg], 0, 0, 0);
        }
        #pragma unroll
        for (int cg = 0; cg < CG; ++cg) {
            int c = wc * (NCOLS / 2) + cg * 16 + l15;
            #pragma unroll
            for (int j = 0; j < 4; ++j)
                C[(size_t)(rbase + lk * 4 + j) * NCOLS + c] = __float2bfloat16(acc[cg][j]);
        }
    }
}

// ---------------- attention scores: s[n,h] = <h[n,h,:], att[h,:]> ----------------

template<int C, int J>
__global__ void score_kernel(const __hip_bfloat16* __restrict__ h, const float* __restrict__ att_src,
                             const float* __restrict__ att_dst,
                             float* __restrict__ s_src, float* __restrict__ s_dst, int n) {
    int idx = blockIdx.x * blockDim.x + threadIdx.x;   // node*4 + head
    if (idx >= n * 4) return;
    int node = idx >> 2, hd = idx & 3;
    const __hip_bfloat16* hp = h + (size_t)node * J + hd * C;
    const float* as = att_src + hd * C;
    const float* ad = att_dst + hd * C;
    float ss = 0.f, sd = 0.f;
    #pragma unroll
    for (int c8 = 0; c8 < C / 8; ++c8) {
        uint4 u = *(const uint4*)&hp[c8 * 8];   // 8 bf16
        const unsigned* uw = (const unsigned*)&u;
        #pragma unroll
        for (int t = 0; t < 4; ++t) {
            int c = c8 * 8 + t * 2;
            float v0 = lo16(uw[t]);
            float v1 = hi16(uw[t]);
            ss += v0 * as[c] + v1 * as[c + 1];
            sd += v0 * ad[c] + v1 * ad[c + 1];
        }
    }
    s_src[idx] = ss;
    s_dst[idx] = sd;
}

// ---------------- per-edge unnormalized softmax weights (CSR order) ----------------

__global__ void edge_p_kernel(const int* __restrict__ csr, const int* __restrict__ csrd,
                              const float* __restrict__ s_src, const float* __restrict__ s_dst,
                              float* __restrict__ p4, int etot) {
    int j = blockIdx.x * blockDim.x + threadIdx.x;
    if (j >= etot) return;
    int s = csr[j], d = csrd[j];
    float4 a = *(const float4*)&s_src[(size_t)s * 4];
    float4 b = *(const float4*)&s_dst[(size_t)d * 4];
    float4 r;
    float e;
    e = a.x + b.x; e = e > 0.f ? e : NEG_SLOPE * e; r.x = __expf(e);
    e = a.y + b.y; e = e > 0.f ? e : NEG_SLOPE * e; r.y = __expf(e);
    e = a.z + b.z; e = e > 0.f ? e : NEG_SLOPE * e; r.z = __expf(e);
    e = a.w + b.w; e = e > 0.f ? e : NEG_SLOPE * e; r.w = __expf(e);
    *(float4*)&p4[(size_t)j * 4] = r;
}

// ---------------- layer-1 aggregation (+bias +ELU), bf16 h ----------------
// wave-uniform scalarization: loop bounds, csr values, row bases -> SGPR.

__global__ __launch_bounds__(256) void agg1_kernel(
        const __hip_bfloat16* __restrict__ h1, const float* __restrict__ p4,
        const int* __restrict__ rowptr, const int* __restrict__ csr,
        const float* __restrict__ b1, __hip_bfloat16* __restrict__ out1) {
    int d = blockIdx.x * 4 + (threadIdx.x >> 6);
    if (d >= N_NODES) return;
    int lane = threadIdx.x & 63;
    int c0 = lane * 2;
    int hd = lane >> 4;
    float accx = 0.f, accy = 0.f, z = 0.f;
    int beg = __builtin_amdgcn_readfirstlane(rowptr[d]);
    int end = __builtin_amdgcn_readfirstlane(rowptr[d + 1]);
    int j = beg;
    for (; j + 7 < end; j += 8) {
        int sv[8]; float qv[8]; unsigned uv[8];
        #pragma unroll
        for (int t = 0; t < 8; ++t) sv[t] = __builtin_amdgcn_readfirstlane(csr[j + t]);
        #pragma unroll
        for (int t = 0; t < 8; ++t) qv[t] = p4[(size_t)(j + t) * 4 + hd];
        #pragma unroll
        for (int t = 0; t < 8; ++t) uv[t] = *(const unsigned*)&h1[(size_t)sv[t] * 128 + c0];
        #pragma unroll
        for (int t = 0; t < 8; ++t) {
            accx += qv[t] * lo16(uv[t]);
            accy += qv[t] * hi16(uv[t]);
            z += qv[t];
        }
    }
    for (; j < end; ++j) {
        int s = __builtin_amdgcn_readfirstlane(csr[j]);
        float q = p4[(size_t)j * 4 + hd];
        unsigned u = *(const unsigned*)&h1[(size_t)s * 128 + c0];
        accx += q * lo16(u);
        accy += q * hi16(u);
        z += q;
    }
    float invz = 1.0f / z;
    float vx = accx * invz + b1[c0];
    float vy = accy * invz + b1[c0 + 1];
    vx = vx > 0.f ? vx : __expf(vx) - 1.0f;   // ELU
    vy = vy > 0.f ? vy : __expf(vy) - 1.0f;
    __hip_bfloat162 o;
    o.x = __float2bfloat16(vx);
    o.y = __float2bfloat16(vy);
    *(__hip_bfloat162*)&out1[(size_t)d * 128 + c0] = o;
}

// ---------------- layer-2 aggregation + head mean + b2 + log_softmax, bf16 h ----------------
// scalarized like agg1; lanes 40..63 duplicate lane 39 (no divergent loads).

__global__ __launch_bounds__(256) void agg2_kernel(
        const __hip_bfloat16* __restrict__ h2, const float* __restrict__ p4,
        const int* __restrict__ rowptr, const int* __restrict__ csr,
        const float* __restrict__ b2, float* __restrict__ out) {
    int d = blockIdx.x * 4 + (threadIdx.x >> 6);
    if (d >= N_NODES) return;
    int lane = threadIdx.x & 63;
    int ll = lane < 40 ? lane : 39;
    int hd = ll / 10;
    int voff = ll * 4;                         // col index within 160-col row
    float ax = 0.f, ay = 0.f, az = 0.f, aw = 0.f, z = 0.f;
    int beg = __builtin_amdgcn_readfirstlane(rowptr[d]);
    int end = __builtin_amdgcn_readfirstlane(rowptr[d + 1]);
    int j = beg;
    for (; j + 7 < end; j += 8) {
        int sv[8]; float qv[8]; uint2 uv[8];
        #pragma unroll
        for (int t = 0; t < 8; ++t) sv[t] = __builtin_amdgcn_readfirstlane(csr[j + t]);
        #pragma unroll
        for (int t = 0; t < 8; ++t) qv[t] = p4[(size_t)(j + t) * 4 + hd];
        #pragma unroll
        for (int t = 0; t < 8; ++t) uv[t] = *(const uint2*)&h2[(size_t)sv[t] * 160 + voff];
        #pragma unroll
        for (int t = 0; t < 8; ++t) {
            ax += qv[t] * lo16(uv[t].x);
            ay += qv[t] * hi16(uv[t].x);
            az += qv[t] * lo16(uv[t].y);
            aw += qv[t] * hi16(uv[t].y);
            z += qv[t];
        }
    }
    for (; j < end; ++j) {
        int s = __builtin_amdgcn_readfirstlane(csr[j]);
        float q = p4[(size_t)j * 4 + hd];
        uint2 u = *(const uint2*)&h2[(size_t)s * 160 + voff];
        ax += q * lo16(u.x);
        ay += q * hi16(u.x);
        az += q * lo16(u.y);
        aw += q * hi16(u.y);
        z += q;
    }
    float invz = 1.0f / z;
    float rx = ax * invz, ry = ay * invz, rz = az * invz, rw = aw * invz;
    float sx = rx + __shfl(rx, lane + 10) + __shfl(rx, lane + 20) + __shfl(rx, lane + 30);
    float sy = ry + __shfl(ry, lane + 10) + __shfl(ry, lane + 20) + __shfl(ry, lane + 30);
    float sz = rz + __shfl(rz, lane + 10) + __shfl(rz, lane + 20) + __shfl(rz, lane + 30);
    float sw = rw + __shfl(rw, lane + 10) + __shfl(rw, lane + 20) + __shfl(rw, lane + 30);
    int lc = lane < 10 ? lane : 9;
    float4 bb = *(const float4*)&b2[lc * 4];
    bool own = lane < 10;
    float vx = own ? sx * 0.25f + bb.x : -1e30f;
    float vy = own ? sy * 0.25f + bb.y : -1e30f;
    float vz = own ? sz * 0.25f + bb.z : -1e30f;
    float vw = own ? sw * 0.25f + bb.w : -1e30f;
    float m = fmaxf(fmaxf(vx, vy), fmaxf(vz, vw));
    #pragma unroll
    for (int off = 1; off < 16; off <<= 1) m = fmaxf(m, __shfl_xor(m, off));
    float ssum = 0.f;
    if (own) {
        ssum = __expf(vx - m) + __expf(vy - m) + __expf(vz - m) + __expf(vw - m);
    }
    #pragma unroll
    for (int off = 1; off < 16; off <<= 1) ssum += __shfl_xor(ssum, off);
    float lse = m + __logf(ssum);
    if (own) {
        float4 o = {vx - lse, vy - lse, vz - lse, vw - lse};
        *(float4*)&out[(size_t)d * 40 + lane * 4] = o;
    }
}

// ---------------- launch ----------------

extern "C" void kernel_launch(void* const* d_in, const int* in_sizes, int n_in,
                              void* d_out, int out_size, void* d_ws, size_t ws_size,
                              hipStream_t stream) {
    const float* x   = (const float*)d_in[0];
    const int*   ei  = (const int*)d_in[1];
    const float* W1  = (const float*)d_in[2];
    const float* as1 = (const float*)d_in[3];
    const float* ad1 = (const float*)d_in[4];
    const float* b1  = (const float*)d_in[5];
    const float* W2  = (const float*)d_in[6];
    const float* as2 = (const float*)d_in[7];
    const float* ad2 = (const float*)d_in[8];
    const float* b2  = (const float*)d_in[9];
    float* out = (float*)d_out;

    char* ws = (char*)d_ws;
    size_t off = 0;
    auto alloc = [&](size_t bytes) {
        void* p = ws + off;
        off += (bytes + 255) & ~(size_t)255;
        return p;
    };
    __hip_bfloat16* h1b   = (__hip_bfloat16*)alloc((size_t)M_PAD * 128 * 2);
    __hip_bfloat16* out1b = (__hip_bfloat16*)alloc((size_t)M_PAD * 128 * 2);
    __hip_bfloat16* h2b   = (__hip_bfloat16*)alloc((size_t)M_PAD * 160 * 2);
    __hip_bfloat16* W1t   = (__hip_bfloat16*)alloc((size_t)128 * 128 * 2);
    __hip_bfloat16* W2t   = (__hip_bfloat16*)alloc((size_t)160 * 128 * 2);
    float* s_src1  = (float*)alloc((size_t)N_NODES * 4 * 4);
    float* s_dst1  = (float*)alloc((size_t)N_NODES * 4 * 4);
    float* s_src2  = (float*)alloc((size_t)N_NODES * 4 * 4);
    float* s_dst2  = (float*)alloc((size_t)N_NODES * 4 * 4);
    float* p4      = (float*)alloc((size_t)E_TOT * 4 * 4);
    int2*  tmp     = (int2*)alloc((size_t)E_TOT * 8);
    int*   rowptr  = (int*)alloc((size_t)(N_NODES + 1) * 4);
    int*   csr     = (int*)alloc((size_t)E_TOT * 4);
    int*   csrd    = (int*)alloc((size_t)E_TOT * 4);
    int*   cnt     = (int*)alloc((size_t)REP * BUCKETS * 4);
    int*   bsum    = (int*)alloc((size_t)BUCKETS * 4);
    int*   boff    = (int*)alloc((size_t)(BUCKETS + 1) * 4);

    // CSR build (sliced counting-sort partition; LDS cursors, no global atomics)
    slice_count_kernel<<<REP, 256, 0, stream>>>(ei, cnt);
    col_scan_kernel<<<BUCKETS, REP, 0, stream>>>(cnt, bsum);
    bucket_scan_kernel<<<1, 1024, 0, stream>>>(bsum, boff);
    bucket_scatter_kernel<<<REP, 256, 0, stream>>>(ei, cnt, boff, tmp);
    bucket_build_kernel<<<BUCKETS, 256, 0, stream>>>(tmp, boff, rowptr, csr, csrd);

    // dtype prep (weights only; x converted inside GEMM1)
    cvt_wt_kernel<<<(128 * 128 + 255) / 256, 256, 0, stream>>>(W1, W1t, 128, 128);
    cvt_wt_kernel<<<(128 * 160 + 255) / 256, 256, 0, stream>>>(W2, W2t, 128, 160);

    // layer 1
    mfma_gemm_f32a_kernel<128><<<M_PAD / 128, 256, 0, stream>>>(x, W1t, h1b);
    score_kernel<32, 128><<<(N_NODES * 4 + 255) / 256, 256, 0, stream>>>(h1b, as1, ad1, s_src1, s_dst1, N_NODES);
    edge_p_kernel<<<(E_TOT + 255) / 256, 256, 0, stream>>>(csr, csrd, s_src1, s_dst1, p4, E_TOT);
    agg1_kernel<<<(N_NODES + 3) / 4, 256, 0, stream>>>(h1b, p4, rowptr, csr, b1, out1b);

    // layer 2
    mfma_gemm_kernel<160><<<M_PAD / 128, 256, 0, stream>>>(out1b, W2t, h2b);
    score_kernel<40, 160><<<(N_NODES * 4 + 255) / 256, 256, 0, stream>>>(h2b, as2, ad2, s_src2, s_dst2, N_NODES);
    edge_p_kernel<<<(E_TOT + 255) / 256, 256, 0, stream>>>(csr, csrd, s_src2, s_dst2, p4, E_TOT);
    agg2_kernel<<<(N_NODES + 3) / 4, 256, 0, stream>>>(h2b, p4, rowptr, csr, b2, out);
}

// Round 8
// 319.037 us; speedup vs baseline: 2.4357x; 1.0161x over previous
//
#include <hip/hip_runtime.h>
#include <hip/hip_bf16.h>

#define N_NODES 100000
#define M_PAD   100096            // 782 * 128, padded row count for MFMA GEMM
#define N_EDGES 1600000
#define E_TOT   (N_EDGES + N_NODES)   // + self loops
#define NEG_SLOPE 0.2f

#define G_NODES 128                                  // nodes per bucket (pow2)
#define BUCKETS ((N_NODES + G_NODES - 1) / G_NODES)  // 782
#define REP 512                                      // slices (one block each)
#define SLICE ((E_TOT + REP - 1) / REP)              // 3321 edges per slice

typedef __attribute__((ext_vector_type(8))) short s16x8;
typedef __attribute__((ext_vector_type(4))) float f32x4;
typedef __attribute__((ext_vector_type(2))) float f32x2;

__device__ __forceinline__ float lo16(unsigned u) { return __uint_as_float(u << 16); }
__device__ __forceinline__ float hi16(unsigned u) { return __uint_as_float(u & 0xffff0000u); }

__device__ __forceinline__ short f2bf(float f) {
    __hip_bfloat16 b = __float2bfloat16(f);
    return *(short*)&b;
}

// ---------------- CSR build: sliced counting-sort partition ----------------

__global__ __launch_bounds__(256) void slice_count_kernel(const int* __restrict__ ei,
                                                          int* __restrict__ cnt) {
    __shared__ int h[BUCKETS];
    for (int i = threadIdx.x; i < BUCKETS; i += 256) h[i] = 0;
    __syncthreads();
    int r = blockIdx.x;
    int lo = r * SLICE, hi = min(lo + SLICE, E_TOT);
    for (int e = lo + threadIdx.x; e < hi; e += 256) {
        int d = (e < N_EDGES) ? ei[N_EDGES + e] : e - N_EDGES;
        atomicAdd(&h[d >> 7], 1);
    }
    __syncthreads();
    for (int i = threadIdx.x; i < BUCKETS; i += 256)
        cnt[(size_t)r * BUCKETS + i] = h[i];
}

__global__ __launch_bounds__(REP) void col_scan_kernel(int* __restrict__ cnt,
                                                       int* __restrict__ bsum) {
    __shared__ int lds[REP];
    int b = blockIdx.x, tid = threadIdx.x;
    int v = cnt[(size_t)tid * BUCKETS + b];
    lds[tid] = v;
    __syncthreads();
    for (int off = 1; off < REP; off <<= 1) {
        int t = (tid >= off) ? lds[tid - off] : 0;
        __syncthreads();
        lds[tid] += t;
        __syncthreads();
    }
    cnt[(size_t)tid * BUCKETS + b] = lds[tid] - v;   // exclusive within column
    if (tid == REP - 1) bsum[b] = lds[tid];
}

__global__ __launch_bounds__(1024) void bucket_scan_kernel(const int* __restrict__ bsum,
                                                           int* __restrict__ boff) {
    __shared__ int lds[1024];
    int tid = threadIdx.x;
    int v = (tid < BUCKETS) ? bsum[tid] : 0;
    lds[tid] = v;
    __syncthreads();
    for (int off = 1; off < 1024; off <<= 1) {
        int t = (tid >= off) ? lds[tid - off] : 0;
        __syncthreads();
        lds[tid] += t;
        __syncthreads();
    }
    if (tid < BUCKETS) boff[tid] = lds[tid] - v;
    if (tid == 0) boff[BUCKETS] = E_TOT;
}

__global__ __launch_bounds__(256) void bucket_scatter_kernel(const int* __restrict__ ei,
                                                             const int* __restrict__ colx,
                                                             const int* __restrict__ boff,
                                                             int2* __restrict__ tmp) {
    __shared__ int lcur[BUCKETS];
    int r = blockIdx.x;
    for (int i = threadIdx.x; i < BUCKETS; i += 256)
        lcur[i] = boff[i] + colx[(size_t)r * BUCKETS + i];
    __syncthreads();
    int lo = r * SLICE, hi = min(lo + SLICE, E_TOT);
    for (int e = lo + threadIdx.x; e < hi; e += 256) {
        int s, d;
        if (e < N_EDGES) { s = ei[e]; d = ei[N_EDGES + e]; }
        else             { s = d = e - N_EDGES; }
        int pos = atomicAdd(&lcur[d >> 7], 1);
        tmp[pos] = make_int2(s, d);
    }
}

__global__ __launch_bounds__(256) void bucket_build_kernel(const int2* __restrict__ tmp,
                                                           const int* __restrict__ boff,
                                                           int* __restrict__ rowptr,
                                                           int* __restrict__ csr,
                                                           int* __restrict__ csrd) {
    __shared__ int hcnt[G_NODES];
    __shared__ int hoff[G_NODES];
    int b = blockIdx.x;
    int base = boff[b], cnt = boff[b + 1] - base;
    int tid = threadIdx.x;
    if (tid < G_NODES) hcnt[tid] = 0;
    __syncthreads();
    for (int i = tid; i < cnt; i += 256)
        atomicAdd(&hcnt[tmp[base + i].y & (G_NODES - 1)], 1);
    __syncthreads();
    if (tid < G_NODES) hoff[tid] = hcnt[tid];
    __syncthreads();
    for (int off = 1; off < G_NODES; off <<= 1) {
        int t = (tid < G_NODES && tid >= off) ? hoff[tid - off] : 0;
        __syncthreads();
        if (tid < G_NODES) hoff[tid] += t;
        __syncthreads();
    }
    if (tid < G_NODES) {
        int excl = hoff[tid] - hcnt[tid];
        int node = b * G_NODES + tid;
        if (node < N_NODES) rowptr[node] = base + excl;
        hcnt[tid] = excl;       // reuse as cursor
    }
    __syncthreads();
    for (int i = tid; i < cnt; i += 256) {
        int2 e = tmp[base + i];
        int pos = base + atomicAdd(&hcnt[e.y & (G_NODES - 1)], 1);
        csr[pos] = e.x;
        csrd[pos] = e.y;
    }
    if (b == 0 && tid == 0) rowptr[N_NODES] = E_TOT;
}

// ---------------- dtype conversion: both weights in one launch ----------------
// W1 [128][128] -> W1t [128][128]; W2 [128][160] -> W2t [160][128]

__global__ void cvt_w_kernel(const float* __restrict__ W1, __hip_bfloat16* __restrict__ W1t,
                             const float* __restrict__ W2, __hip_bfloat16* __restrict__ W2t) {
    int idx = blockIdx.x * blockDim.x + threadIdx.x;
    if (idx < 128 * 128) {
        int k = idx >> 7, n = idx & 127;
        W1t[n * 128 + k] = __float2bfloat16(W1[idx]);
    } else if (idx < 128 * 128 + 128 * 160) {
        int i = idx - 128 * 128;
        int k = i / 160, n = i - k * 160;
        W2t[n * 128 + k] = __float2bfloat16(W2[i]);
    }
}

// ---------------- MFMA GEMM (layer 1): A is f32, converted in-register ----------------

template<int NCOLS>
__global__ __launch_bounds__(256) void mfma_gemm_f32a_kernel(const float* __restrict__ A,
                                                             const __hip_bfloat16* __restrict__ Bt,
                                                             __hip_bfloat16* __restrict__ C) {
    constexpr int CG = NCOLS / 32;
    int wid = threadIdx.x >> 6;
    int lane = threadIdx.x & 63;
    int wr = wid >> 1, wc = wid & 1;
    int l15 = lane & 15, lk = lane >> 4;

    s16x8 bfrag[CG][4];
    #pragma unroll
    for (int cg = 0; cg < CG; ++cg) {
        int col = wc * (NCOLS / 2) + cg * 16 + l15;
        #pragma unroll
        for (int ks = 0; ks < 4; ++ks)
            bfrag[cg][ks] = *(const s16x8*)&Bt[col * 128 + ks * 32 + lk * 8];
    }
    int rowblk = blockIdx.x * 128;
    #pragma unroll
    for (int st = 0; st < 4; ++st) {
        int rbase = rowblk + st * 32 + wr * 16;
        int row = rbase + l15;
        bool ok = row < N_NODES;
        s16x8 afrag[4];
        #pragma unroll
        for (int ks = 0; ks < 4; ++ks) {
            if (ok) {
                float4 a0 = *(const float4*)&A[(size_t)row * 128 + ks * 32 + lk * 8];
                float4 a1 = *(const float4*)&A[(size_t)row * 128 + ks * 32 + lk * 8 + 4];
                s16x8 af;
                af[0] = f2bf(a0.x); af[1] = f2bf(a0.y); af[2] = f2bf(a0.z); af[3] = f2bf(a0.w);
                af[4] = f2bf(a1.x); af[5] = f2bf(a1.y); af[6] = f2bf(a1.z); af[7] = f2bf(a1.w);
                afrag[ks] = af;
            } else {
                afrag[ks] = (s16x8){0,0,0,0,0,0,0,0};
            }
        }
        f32x4 acc[CG];
        #pragma unroll
        for (int cg = 0; cg < CG; ++cg) acc[cg] = (f32x4){0.f, 0.f, 0.f, 0.f};
        #pragma unroll
        for (int ks = 0; ks < 4; ++ks) {
            #pragma unroll
            for (int cg = 0; cg < CG; ++cg)
                acc[cg] = __builtin_amdgcn_mfma_f32_16x16x32_bf16(afrag[ks], bfrag[cg][ks], acc[cg], 0, 0, 0);
        }
        #pragma unroll
        for (int cg = 0; cg < CG; ++cg) {
            int c = wc * (NCOLS / 2) + cg * 16 + l15;
            #pragma unroll
            for (int j = 0; j < 4; ++j)
                C[(size_t)(rbase + lk * 4 + j) * NCOLS + c] = __float2bfloat16(acc[cg][j]);
        }
    }
}

// ---------------- MFMA GEMM (layer 2): bf16 A ----------------

template<int NCOLS>
__global__ __launch_bounds__(256) void mfma_gemm_kernel(const __hip_bfloat16* __restrict__ A,
                                                        const __hip_bfloat16* __restrict__ Bt,
                                                        __hip_bfloat16* __restrict__ C) {
    constexpr int CG = NCOLS / 32;
    int wid = threadIdx.x >> 6;
    int lane = threadIdx.x & 63;
    int wr = wid >> 1, wc = wid & 1;
    int l15 = lane & 15, lk = lane >> 4;

    s16x8 bfrag[CG][4];
    #pragma unroll
    for (int cg = 0; cg < CG; ++cg) {
        int col = wc * (NCOLS / 2) + cg * 16 + l15;
        #pragma unroll
        for (int ks = 0; ks < 4; ++ks)
            bfrag[cg][ks] = *(const s16x8*)&Bt[col * 128 + ks * 32 + lk * 8];
    }
    int rowblk = blockIdx.x * 128;
    #pragma unroll
    for (int st = 0; st < 4; ++st) {
        int rbase = rowblk + st * 32 + wr * 16;
        s16x8 afrag[4];
        #pragma unroll
        for (int ks = 0; ks < 4; ++ks)
            afrag[ks] = *(const s16x8*)&A[(size_t)(rbase + l15) * 128 + ks * 32 + lk * 8];
        f32x4 acc[CG];
        #pragma unroll
        for (int cg = 0; cg < CG; ++cg) acc[cg] = (f32x4){0.f, 0.f, 0.f, 0.f};
        #pragma unroll
        for (int ks = 0; ks < 4; ++ks) {
            #pragma unroll
            for (int cg = 0; cg < CG; ++cg)
                acc[cg] = __builtin_amdgcn_mfma_f32_16x16x32_bf16(afrag[ks], bfrag[cg][ks], acc[cg], 0, 0, 0);
        }
        #pragma unroll
        for (int cg = 0; cg < CG; ++cg) {
            int c = wc * (NCOLS / 2) + cg * 16 + l15;
            #pragma unroll
            for (int j = 0; j < 4; ++j)
                C[(size_t)(rbase + lk * 4 + j) * NCOLS + c] = __float2bfloat16(acc[cg][j]);
        }
    }
}

// ---------------- attention scores ----------------

template<int C, int J>
__global__ void score_kernel(const __hip_bfloat16* __restrict__ h, const float* __restrict__ att_src,
                             const float* __restrict__ att_dst,
                             float* __restrict__ s_src, float* __restrict__ s_dst, int n) {
    int idx = blockIdx.x * blockDim.x + threadIdx.x;   // node*4 + head
    if (idx >= n * 4) return;
    int node = idx >> 2, hd = idx & 3;
    const __hip_bfloat16* hp = h + (size_t)node * J + hd * C;
    const float* as = att_src + hd * C;
    const float* ad = att_dst + hd * C;
    float ss = 0.f, sd = 0.f;
    #pragma unroll
    for (int c8 = 0; c8 < C / 8; ++c8) {
        uint4 u = *(const uint4*)&hp[c8 * 8];   // 8 bf16
        const unsigned* uw = (const unsigned*)&u;
        #pragma unroll
        for (int t = 0; t < 4; ++t) {
            int c = c8 * 8 + t * 2;
            float v0 = lo16(uw[t]);
            float v1 = hi16(uw[t]);
            ss += v0 * as[c] + v1 * as[c + 1];
            sd += v0 * ad[c] + v1 * ad[c + 1];
        }
    }
    s_src[idx] = ss;
    s_dst[idx] = sd;
}

// ---------------- per-edge unnormalized softmax weights (CSR order) ----------------

__global__ void edge_p_kernel(const int* __restrict__ csr, const int* __restrict__ csrd,
                              const float* __restrict__ s_src, const float* __restrict__ s_dst,
                              float* __restrict__ p4, int etot) {
    int j = blockIdx.x * blockDim.x + threadIdx.x;
    if (j >= etot) return;
    int s = csr[j], d = csrd[j];
    float4 a = *(const float4*)&s_src[(size_t)s * 4];
    float4 b = *(const float4*)&s_dst[(size_t)d * 4];
    float4 r;
    float e;
    e = a.x + b.x; e = e > 0.f ? e : NEG_SLOPE * e; r.x = __expf(e);
    e = a.y + b.y; e = e > 0.f ? e : NEG_SLOPE * e; r.y = __expf(e);
    e = a.z + b.z; e = e > 0.f ? e : NEG_SLOPE * e; r.z = __expf(e);
    e = a.w + b.w; e = e > 0.f ? e : NEG_SLOPE * e; r.w = __expf(e);
    *(float4*)&p4[(size_t)j * 4] = r;
}

// ---------------- layer-1 aggregation (+bias +ELU), bf16 h ----------------
// Uniform row pointers (SALU address math) + f32x2 packed accumulate.

__global__ __launch_bounds__(256) void agg1_kernel(
        const __hip_bfloat16* __restrict__ h1, const float* __restrict__ p4,
        const int* __restrict__ rowptr, const int* __restrict__ csr,
        const float* __restrict__ b1, __hip_bfloat16* __restrict__ out1) {
    int d = blockIdx.x * 4 + (threadIdx.x >> 6);
    if (d >= N_NODES) return;
    int lane = threadIdx.x & 63;
    int c0 = lane * 2;
    int hd = lane >> 4;
    f32x2 acc = {0.f, 0.f};
    float z = 0.f;
    int beg = __builtin_amdgcn_readfirstlane(rowptr[d]);
    int end = __builtin_amdgcn_readfirstlane(rowptr[d + 1]);
    int j = beg;
    for (; j + 3 < end; j += 4) {
        #pragma unroll
        for (int t = 0; t < 4; ++t) {
            int s = __builtin_amdgcn_readfirstlane(csr[j + t]);
            const float* pj = p4 + (size_t)(j + t) * 4;          // uniform
            const __hip_bfloat16* row = h1 + (size_t)s * 128;    // uniform
            float q = pj[hd];
            unsigned u = *(const unsigned*)&row[c0];
            f32x2 v = {lo16(u), hi16(u)};
            f32x2 qq = {q, q};
            acc += qq * v;
            z += q;
        }
    }
    for (; j < end; ++j) {
        int s = __builtin_amdgcn_readfirstlane(csr[j]);
        const float* pj = p4 + (size_t)j * 4;
        const __hip_bfloat16* row = h1 + (size_t)s * 128;
        float q = pj[hd];
        unsigned u = *(const unsigned*)&row[c0];
        f32x2 v = {lo16(u), hi16(u)};
        f32x2 qq = {q, q};
        acc += qq * v;
        z += q;
    }
    float invz = 1.0f / z;
    float vx = acc.x * invz + b1[c0];
    float vy = acc.y * invz + b1[c0 + 1];
    vx = vx > 0.f ? vx : __expf(vx) - 1.0f;   // ELU
    vy = vy > 0.f ? vy : __expf(vy) - 1.0f;
    __hip_bfloat162 o;
    o.x = __float2bfloat16(vx);
    o.y = __float2bfloat16(vy);
    *(__hip_bfloat162*)&out1[(size_t)d * 128 + c0] = o;
}

// ---------------- layer-2 aggregation + head mean + b2 + log_softmax ----------------

__global__ __launch_bounds__(256) void agg2_kernel(
        const __hip_bfloat16* __restrict__ h2, const float* __restrict__ p4,
        const int* __restrict__ rowptr, const int* __restrict__ csr,
        const float* __restrict__ b2, float* __restrict__ out) {
    int d = blockIdx.x * 4 + (threadIdx.x >> 6);
    if (d >= N_NODES) return;
    int lane = threadIdx.x & 63;
    int ll = lane < 40 ? lane : 39;
    int hd = ll / 10;
    int voff = ll * 4;                         // col index within 160-col row
    f32x2 acc01 = {0.f, 0.f}, acc23 = {0.f, 0.f};
    float z = 0.f;
    int beg = __builtin_amdgcn_readfirstlane(rowptr[d]);
    int end = __builtin_amdgcn_readfirstlane(rowptr[d + 1]);
    int j = beg;
    for (; j + 3 < end; j += 4) {
        #pragma unroll
        for (int t = 0; t < 4; ++t) {
            int s = __builtin_amdgcn_readfirstlane(csr[j + t]);
            const float* pj = p4 + (size_t)(j + t) * 4;          // uniform
            const __hip_bfloat16* row = h2 + (size_t)s * 160;    // uniform
            float q = pj[hd];
            uint2 u = *(const uint2*)&row[voff];
            f32x2 v01 = {lo16(u.x), hi16(u.x)};
            f32x2 v23 = {lo16(u.y), hi16(u.y)};
            f32x2 qq = {q, q};
            acc01 += qq * v01;
            acc23 += qq * v23;
            z += q;
        }
    }
    for (; j < end; ++j) {
        int s = __builtin_amdgcn_readfirstlane(csr[j]);
        const float* pj = p4 + (size_t)j * 4;
        const __hip_bfloat16* row = h2 + (size_t)s * 160;
        float q = pj[hd];
        uint2 u = *(const uint2*)&row[voff];
        f32x2 v01 = {lo16(u.x), hi16(u.x)};
        f32x2 v23 = {lo16(u.y), hi16(u.y)};
        f32x2 qq = {q, q};
        acc01 += qq * v01;
        acc23 += qq * v23;
        z += q;
    }
    float invz = 1.0f / z;
    float rx = acc01.x * invz, ry = acc01.y * invz;
    float rz = acc23.x * invz, rw = acc23.y * invz;
    float sx = rx + __shfl(rx, lane + 10) + __shfl(rx, lane + 20) + __shfl(rx, lane + 30);
    float sy = ry + __shfl(ry, lane + 10) + __shfl(ry, lane + 20) + __shfl(ry, lane + 30);
    float sz = rz + __shfl(rz, lane + 10) + __shfl(rz, lane + 20) + __shfl(rz, lane + 30);
    float sw = rw + __shfl(rw, lane + 10) + __shfl(rw, lane + 20) + __shfl(rw, lane + 30);
    int lc = lane < 10 ? lane : 9;
    float4 bb = *(const float4*)&b2[lc * 4];
    bool own = lane < 10;
    float vx = own ? sx * 0.25f + bb.x : -1e30f;
    float vy = own ? sy * 0.25f + bb.y : -1e30f;
    float vz = own ? sz * 0.25f + bb.z : -1e30f;
    float vw = own ? sw * 0.25f + bb.w : -1e30f;
    float m = fmaxf(fmaxf(vx, vy), fmaxf(vz, vw));
    #pragma unroll
    for (int off = 1; off < 16; off <<= 1) m = fmaxf(m, __shfl_xor(m, off));
    float ssum = 0.f;
    if (own) {
        ssum = __expf(vx - m) + __expf(vy - m) + __expf(vz - m) + __expf(vw - m);
    }
    #pragma unroll
    for (int off = 1; off < 16; off <<= 1) ssum += __shfl_xor(ssum, off);
    float lse = m + __logf(ssum);
    if (own) {
        float4 o = {vx - lse, vy - lse, vz - lse, vw - lse};
        *(float4*)&out[(size_t)d * 40 + lane * 4] = o;
    }
}

// ---------------- launch ----------------

extern "C" void kernel_launch(void* const* d_in, const int* in_sizes, int n_in,
                              void* d_out, int out_size, void* d_ws, size_t ws_size,
                              hipStream_t stream) {
    const float* x   = (const float*)d_in[0];
    const int*   ei  = (const int*)d_in[1];
    const float* W1  = (const float*)d_in[2];
    const float* as1 = (const float*)d_in[3];
    const float* ad1 = (const float*)d_in[4];
    const float* b1  = (const float*)d_in[5];
    const float* W2  = (const float*)d_in[6];
    const float* as2 = (const float*)d_in[7];
    const float* ad2 = (const float*)d_in[8];
    const float* b2  = (const float*)d_in[9];
    float* out = (float*)d_out;

    char* ws = (char*)d_ws;
    size_t off = 0;
    auto alloc = [&](size_t bytes) {
        void* p = ws + off;
        off += (bytes + 255) & ~(size_t)255;
        return p;
    };
    __hip_bfloat16* h1b   = (__hip_bfloat16*)alloc((size_t)M_PAD * 128 * 2);
    __hip_bfloat16* out1b = (__hip_bfloat16*)alloc((size_t)M_PAD * 128 * 2);
    __hip_bfloat16* h2b   = (__hip_bfloat16*)alloc((size_t)M_PAD * 160 * 2);
    __hip_bfloat16* W1t   = (__hip_bfloat16*)alloc((size_t)128 * 128 * 2);
    __hip_bfloat16* W2t   = (__hip_bfloat16*)alloc((size_t)160 * 128 * 2);
    float* s_src1  = (float*)alloc((size_t)N_NODES * 4 * 4);
    float* s_dst1  = (float*)alloc((size_t)N_NODES * 4 * 4);
    float* s_src2  = (float*)alloc((size_t)N_NODES * 4 * 4);
    float* s_dst2  = (float*)alloc((size_t)N_NODES * 4 * 4);
    float* p4      = (float*)alloc((size_t)E_TOT * 4 * 4);
    int2*  tmp     = (int2*)alloc((size_t)E_TOT * 8);
    int*   rowptr  = (int*)alloc((size_t)(N_NODES + 1) * 4);
    int*   csr     = (int*)alloc((size_t)E_TOT * 4);
    int*   csrd    = (int*)alloc((size_t)E_TOT * 4);
    int*   cnt     = (int*)alloc((size_t)REP * BUCKETS * 4);
    int*   bsum    = (int*)alloc((size_t)BUCKETS * 4);
    int*   boff    = (int*)alloc((size_t)(BUCKETS + 1) * 4);

    // CSR build (sliced counting-sort partition; LDS cursors, no global atomics)
    slice_count_kernel<<<REP, 256, 0, stream>>>(ei, cnt);
    col_scan_kernel<<<BUCKETS, REP, 0, stream>>>(cnt, bsum);
    bucket_scan_kernel<<<1, 1024, 0, stream>>>(bsum, boff);
    bucket_scatter_kernel<<<REP, 256, 0, stream>>>(ei, cnt, boff, tmp);
    bucket_build_kernel<<<BUCKETS, 256, 0, stream>>>(tmp, boff, rowptr, csr, csrd);

    // dtype prep (weights only; x converted inside GEMM1)
    cvt_w_kernel<<<(128 * 128 + 128 * 160 + 255) / 256, 256, 0, stream>>>(W1, W1t, W2, W2t);

    // layer 1
    mfma_gemm_f32a_kernel<128><<<M_PAD / 128, 256, 0, stream>>>(x, W1t, h1b);
    score_kernel<32, 128><<<(N_NODES * 4 + 255) / 256, 256, 0, stream>>>(h1b, as1, ad1, s_src1, s_dst1, N_NODES);
    edge_p_kernel<<<(E_TOT + 255) / 256, 256, 0, stream>>>(csr, csrd, s_src1, s_dst1, p4, E_TOT);
    agg1_kernel<<<(N_NODES + 3) / 4, 256, 0, stream>>>(h1b, p4, rowptr, csr, b1, out1b);

    // layer 2
    mfma_gemm_kernel<160><<<M_PAD / 128, 256, 0, stream>>>(out1b, W2t, h2b);
    score_kernel<40, 160><<<(N_NODES * 4 + 255) / 256, 256, 0, stream>>>(h2b, as2, ad2, s_src2, s_dst2, N_NODES);
    edge_p_kernel<<<(E_TOT + 255) / 256, 256, 0, stream>>>(csr, csrd, s_src2, s_dst2, p4, E_TOT);
    agg2_kernel<<<(N_NODES + 3) / 4, 256, 0, stream>>>(h2b, p4, rowptr, csr, b2, out);
}

// Round 9
// 307.787 us; speedup vs baseline: 2.5247x; 1.0365x over previous
//
#include <hip/hip_runtime.h>
#include <hip/hip_bf16.h>

#define N_NODES 100000
#define M_PAD   100096            // 782 * 128, padded row count for MFMA GEMM
#define N_EDGES 1600000
#define E_TOT   (N_EDGES + N_NODES)   // + self loops
#define NEG_SLOPE 0.2f

#define G_NODES 128                                  // nodes per bucket (pow2)
#define BUCKETS ((N_NODES + G_NODES - 1) / G_NODES)  // 782
#define REP 512                                      // slices (one block each)
#define SLICE ((E_TOT + REP - 1) / REP)              // 3321 edges per slice

typedef __attribute__((ext_vector_type(8))) short s16x8;
typedef __attribute__((ext_vector_type(4))) float f32x4;
typedef __attribute__((ext_vector_type(2))) float f32x2;

__device__ __forceinline__ float lo16(unsigned u) { return __uint_as_float(u << 16); }
__device__ __forceinline__ float hi16(unsigned u) { return __uint_as_float(u & 0xffff0000u); }

__device__ __forceinline__ short f2bf(float f) {
    __hip_bfloat16 b = __float2bfloat16(f);
    return *(short*)&b;
}

// ---------------- CSR build: sliced counting-sort partition ----------------

__global__ __launch_bounds__(256) void slice_count_kernel(const int* __restrict__ ei,
                                                          int* __restrict__ cnt) {
    __shared__ int h[BUCKETS];
    for (int i = threadIdx.x; i < BUCKETS; i += 256) h[i] = 0;
    __syncthreads();
    int r = blockIdx.x;
    int lo = r * SLICE, hi = min(lo + SLICE, E_TOT);
    for (int e = lo + threadIdx.x; e < hi; e += 256) {
        int d = (e < N_EDGES) ? ei[N_EDGES + e] : e - N_EDGES;
        atomicAdd(&h[d >> 7], 1);
    }
    __syncthreads();
    for (int i = threadIdx.x; i < BUCKETS; i += 256)
        cnt[(size_t)r * BUCKETS + i] = h[i];
}

__global__ __launch_bounds__(REP) void col_scan_kernel(int* __restrict__ cnt,
                                                       int* __restrict__ bsum) {
    __shared__ int lds[REP];
    int b = blockIdx.x, tid = threadIdx.x;
    int v = cnt[(size_t)tid * BUCKETS + b];
    lds[tid] = v;
    __syncthreads();
    for (int off = 1; off < REP; off <<= 1) {
        int t = (tid >= off) ? lds[tid - off] : 0;
        __syncthreads();
        lds[tid] += t;
        __syncthreads();
    }
    cnt[(size_t)tid * BUCKETS + b] = lds[tid] - v;   // exclusive within column
    if (tid == REP - 1) bsum[b] = lds[tid];
}

__global__ __launch_bounds__(1024) void bucket_scan_kernel(const int* __restrict__ bsum,
                                                           int* __restrict__ boff) {
    __shared__ int lds[1024];
    int tid = threadIdx.x;
    int v = (tid < BUCKETS) ? bsum[tid] : 0;
    lds[tid] = v;
    __syncthreads();
    for (int off = 1; off < 1024; off <<= 1) {
        int t = (tid >= off) ? lds[tid - off] : 0;
        __syncthreads();
        lds[tid] += t;
        __syncthreads();
    }
    if (tid < BUCKETS) boff[tid] = lds[tid] - v;
    if (tid == 0) boff[BUCKETS] = E_TOT;
}

__global__ __launch_bounds__(256) void bucket_scatter_kernel(const int* __restrict__ ei,
                                                             const int* __restrict__ colx,
                                                             const int* __restrict__ boff,
                                                             int2* __restrict__ tmp) {
    __shared__ int lcur[BUCKETS];
    int r = blockIdx.x;
    for (int i = threadIdx.x; i < BUCKETS; i += 256)
        lcur[i] = boff[i] + colx[(size_t)r * BUCKETS + i];
    __syncthreads();
    int lo = r * SLICE, hi = min(lo + SLICE, E_TOT);
    for (int e = lo + threadIdx.x; e < hi; e += 256) {
        int s, d;
        if (e < N_EDGES) { s = ei[e]; d = ei[N_EDGES + e]; }
        else             { s = d = e - N_EDGES; }
        int pos = atomicAdd(&lcur[d >> 7], 1);
        tmp[pos] = make_int2(s, d);
    }
}

__global__ __launch_bounds__(256) void bucket_build_kernel(const int2* __restrict__ tmp,
                                                           const int* __restrict__ boff,
                                                           int* __restrict__ rowptr,
                                                           int* __restrict__ csr,
                                                           int* __restrict__ csrd) {
    __shared__ int hcnt[G_NODES];
    __shared__ int hoff[G_NODES];
    int b = blockIdx.x;
    int base = boff[b], cnt = boff[b + 1] - base;
    int tid = threadIdx.x;
    if (tid < G_NODES) hcnt[tid] = 0;
    __syncthreads();
    for (int i = tid; i < cnt; i += 256)
        atomicAdd(&hcnt[tmp[base + i].y & (G_NODES - 1)], 1);
    __syncthreads();
    if (tid < G_NODES) hoff[tid] = hcnt[tid];
    __syncthreads();
    for (int off = 1; off < G_NODES; off <<= 1) {
        int t = (tid < G_NODES && tid >= off) ? hoff[tid - off] : 0;
        __syncthreads();
        if (tid < G_NODES) hoff[tid] += t;
        __syncthreads();
    }
    if (tid < G_NODES) {
        int excl = hoff[tid] - hcnt[tid];
        int node = b * G_NODES + tid;
        if (node < N_NODES) rowptr[node] = base + excl;
        hcnt[tid] = excl;       // reuse as cursor
    }
    __syncthreads();
    for (int i = tid; i < cnt; i += 256) {
        int2 e = tmp[base + i];
        int pos = base + atomicAdd(&hcnt[e.y & (G_NODES - 1)], 1);
        csr[pos] = e.x;
        csrd[pos] = e.y;
    }
    if (b == 0 && tid == 0) rowptr[N_NODES] = E_TOT;
}

// ---------------- dtype conversion: both weights in one launch ----------------

__global__ void cvt_w_kernel(const float* __restrict__ W1, __hip_bfloat16* __restrict__ W1t,
                             const float* __restrict__ W2, __hip_bfloat16* __restrict__ W2t) {
    int idx = blockIdx.x * blockDim.x + threadIdx.x;
    if (idx < 128 * 128) {
        int k = idx >> 7, n = idx & 127;
        W1t[n * 128 + k] = __float2bfloat16(W1[idx]);
    } else if (idx < 128 * 128 + 128 * 160) {
        int i = idx - 128 * 128;
        int k = i / 160, n = i - k * 160;
        W2t[n * 128 + k] = __float2bfloat16(W2[i]);
    }
}

// ---------------- bf16 h -> fp8 (e4m3) gather copy ----------------
// thread handles 8 elems: uint4 (8 bf16) -> uint2 (8 fp8)

__global__ __launch_bounds__(256) void cvt_h_fp8_kernel(const __hip_bfloat16* __restrict__ in,
                                                        unsigned* __restrict__ out, int n8) {
    int i = blockIdx.x * blockDim.x + threadIdx.x;
    if (i >= n8) return;
    uint4 u = ((const uint4*)in)[i];
    const unsigned* uw = (const unsigned*)&u;
    unsigned d0 = 0, d1 = 0;
    d0 = __builtin_amdgcn_cvt_pk_fp8_f32(lo16(uw[0]), hi16(uw[0]), d0, false);
    d0 = __builtin_amdgcn_cvt_pk_fp8_f32(lo16(uw[1]), hi16(uw[1]), d0, true);
    d1 = __builtin_amdgcn_cvt_pk_fp8_f32(lo16(uw[2]), hi16(uw[2]), d1, false);
    d1 = __builtin_amdgcn_cvt_pk_fp8_f32(lo16(uw[3]), hi16(uw[3]), d1, true);
    out[(size_t)i * 2]     = d0;
    out[(size_t)i * 2 + 1] = d1;
}

// ---------------- MFMA GEMM (layer 1): A is f32, converted in-register ----------------

template<int NCOLS>
__global__ __launch_bounds__(256) void mfma_gemm_f32a_kernel(const float* __restrict__ A,
                                                             const __hip_bfloat16* __restrict__ Bt,
                                                             __hip_bfloat16* __restrict__ C) {
    constexpr int CG = NCOLS / 32;
    int wid = threadIdx.x >> 6;
    int lane = threadIdx.x & 63;
    int wr = wid >> 1, wc = wid & 1;
    int l15 = lane & 15, lk = lane >> 4;

    s16x8 bfrag[CG][4];
    #pragma unroll
    for (int cg = 0; cg < CG; ++cg) {
        int col = wc * (NCOLS / 2) + cg * 16 + l15;
        #pragma unroll
        for (int ks = 0; ks < 4; ++ks)
            bfrag[cg][ks] = *(const s16x8*)&Bt[col * 128 + ks * 32 + lk * 8];
    }
    int rowblk = blockIdx.x * 128;
    #pragma unroll
    for (int st = 0; st < 4; ++st) {
        int rbase = rowblk + st * 32 + wr * 16;
        int row = rbase + l15;
        bool ok = row < N_NODES;
        s16x8 afrag[4];
        #pragma unroll
        for (int ks = 0; ks < 4; ++ks) {
            if (ok) {
                float4 a0 = *(const float4*)&A[(size_t)row * 128 + ks * 32 + lk * 8];
                float4 a1 = *(const float4*)&A[(size_t)row * 128 + ks * 32 + lk * 8 + 4];
                s16x8 af;
                af[0] = f2bf(a0.x); af[1] = f2bf(a0.y); af[2] = f2bf(a0.z); af[3] = f2bf(a0.w);
                af[4] = f2bf(a1.x); af[5] = f2bf(a1.y); af[6] = f2bf(a1.z); af[7] = f2bf(a1.w);
                afrag[ks] = af;
            } else {
                afrag[ks] = (s16x8){0,0,0,0,0,0,0,0};
            }
        }
        f32x4 acc[CG];
        #pragma unroll
        for (int cg = 0; cg < CG; ++cg) acc[cg] = (f32x4){0.f, 0.f, 0.f, 0.f};
        #pragma unroll
        for (int ks = 0; ks < 4; ++ks) {
            #pragma unroll
            for (int cg = 0; cg < CG; ++cg)
                acc[cg] = __builtin_amdgcn_mfma_f32_16x16x32_bf16(afrag[ks], bfrag[cg][ks], acc[cg], 0, 0, 0);
        }
        #pragma unroll
        for (int cg = 0; cg < CG; ++cg) {
            int c = wc * (NCOLS / 2) + cg * 16 + l15;
            #pragma unroll
            for (int j = 0; j < 4; ++j)
                C[(size_t)(rbase + lk * 4 + j) * NCOLS + c] = __float2bfloat16(acc[cg][j]);
        }
    }
}

// ---------------- MFMA GEMM (layer 2): bf16 A ----------------

template<int NCOLS>
__global__ __launch_bounds__(256) void mfma_gemm_kernel(const __hip_bfloat16* __restrict__ A,
                                                        const __hip_bfloat16* __restrict__ Bt,
                                                        __hip_bfloat16* __restrict__ C) {
    constexpr int CG = NCOLS / 32;
    int wid = threadIdx.x >> 6;
    int lane = threadIdx.x & 63;
    int wr = wid >> 1, wc = wid & 1;
    int l15 = lane & 15, lk = lane >> 4;

    s16x8 bfrag[CG][4];
    #pragma unroll
    for (int cg = 0; cg < CG; ++cg) {
        int col = wc * (NCOLS / 2) + cg * 16 + l15;
        #pragma unroll
        for (int ks = 0; ks < 4; ++ks)
            bfrag[cg][ks] = *(const s16x8*)&Bt[col * 128 + ks * 32 + lk * 8];
    }
    int rowblk = blockIdx.x * 128;
    #pragma unroll
    for (int st = 0; st < 4; ++st) {
        int rbase = rowblk + st * 32 + wr * 16;
        s16x8 afrag[4];
        #pragma unroll
        for (int ks = 0; ks < 4; ++ks)
            afrag[ks] = *(const s16x8*)&A[(size_t)(rbase + l15) * 128 + ks * 32 + lk * 8];
        f32x4 acc[CG];
        #pragma unroll
        for (int cg = 0; cg < CG; ++cg) acc[cg] = (f32x4){0.f, 0.f, 0.f, 0.f};
        #pragma unroll
        for (int ks = 0; ks < 4; ++ks) {
            #pragma unroll
            for (int cg = 0; cg < CG; ++cg)
                acc[cg] = __builtin_amdgcn_mfma_f32_16x16x32_bf16(afrag[ks], bfrag[cg][ks], acc[cg], 0, 0, 0);
        }
        #pragma unroll
        for (int cg = 0; cg < CG; ++cg) {
            int c = wc * (NCOLS / 2) + cg * 16 + l15;
            #pragma unroll
            for (int j = 0; j < 4; ++j)
                C[(size_t)(rbase + lk * 4 + j) * NCOLS + c] = __float2bfloat16(acc[cg][j]);
        }
    }
}

// ---------------- attention scores (bf16 h, unchanged precision) ----------------

template<int C, int J>
__global__ void score_kernel(const __hip_bfloat16* __restrict__ h, const float* __restrict__ att_src,
                             const float* __restrict__ att_dst,
                             float* __restrict__ s_src, float* __restrict__ s_dst, int n) {
    int idx = blockIdx.x * blockDim.x + threadIdx.x;   // node*4 + head
    if (idx >= n * 4) return;
    int node = idx >> 2, hd = idx & 3;
    const __hip_bfloat16* hp = h + (size_t)node * J + hd * C;
    const float* as = att_src + hd * C;
    const float* ad = att_dst + hd * C;
    float ss = 0.f, sd = 0.f;
    #pragma unroll
    for (int c8 = 0; c8 < C / 8; ++c8) {
        uint4 u = *(const uint4*)&hp[c8 * 8];   // 8 bf16
        const unsigned* uw = (const unsigned*)&u;
        #pragma unroll
        for (int t = 0; t < 4; ++t) {
            int c = c8 * 8 + t * 2;
            float v0 = lo16(uw[t]);
            float v1 = hi16(uw[t]);
            ss += v0 * as[c] + v1 * as[c + 1];
            sd += v0 * ad[c] + v1 * ad[c + 1];
        }
    }
    s_src[idx] = ss;
    s_dst[idx] = sd;
}

// ---------------- per-edge unnormalized softmax weights (CSR order) ----------------

__global__ void edge_p_kernel(const int* __restrict__ csr, const int* __restrict__ csrd,
                              const float* __restrict__ s_src, const float* __restrict__ s_dst,
                              float* __restrict__ p4, int etot) {
    int j = blockIdx.x * blockDim.x + threadIdx.x;
    if (j >= etot) return;
    int s = csr[j], d = csrd[j];
    float4 a = *(const float4*)&s_src[(size_t)s * 4];
    float4 b = *(const float4*)&s_dst[(size_t)d * 4];
    float4 r;
    float e;
    e = a.x + b.x; e = e > 0.f ? e : NEG_SLOPE * e; r.x = __expf(e);
    e = a.y + b.y; e = e > 0.f ? e : NEG_SLOPE * e; r.y = __expf(e);
    e = a.z + b.z; e = e > 0.f ? e : NEG_SLOPE * e; r.z = __expf(e);
    e = a.w + b.w; e = e > 0.f ? e : NEG_SLOPE * e; r.w = __expf(e);
    *(float4*)&p4[(size_t)j * 4] = r;
}

// ---------------- layer-1 aggregation (+bias +ELU), fp8 value gather ----------------

__global__ __launch_bounds__(256) void agg1_kernel(
        const unsigned char* __restrict__ h1q, const float* __restrict__ p4,
        const int* __restrict__ rowptr, const int* __restrict__ csr,
        const float* __restrict__ b1, __hip_bfloat16* __restrict__ out1) {
    int d = blockIdx.x * 4 + (threadIdx.x >> 6);
    if (d >= N_NODES) return;
    int lane = threadIdx.x & 63;
    int c0 = lane * 2;
    int hd = lane >> 4;
    f32x2 acc = {0.f, 0.f};
    float z = 0.f;
    int beg = __builtin_amdgcn_readfirstlane(rowptr[d]);
    int end = __builtin_amdgcn_readfirstlane(rowptr[d + 1]);
    int j = beg;
    for (; j + 3 < end; j += 4) {
        #pragma unroll
        for (int t = 0; t < 4; ++t) {
            int s = __builtin_amdgcn_readfirstlane(csr[j + t]);
            const float* pj = p4 + (size_t)(j + t) * 4;              // uniform
            const unsigned char* row = h1q + (size_t)s * 128;        // uniform
            float q = pj[hd];
            unsigned u = *(const unsigned short*)&row[c0];
            f32x2 v = __builtin_amdgcn_cvt_pk_f32_fp8(u, false);
            f32x2 qq = {q, q};
            acc += qq * v;
            z += q;
        }
    }
    for (; j < end; ++j) {
        int s = __builtin_amdgcn_readfirstlane(csr[j]);
        const float* pj = p4 + (size_t)j * 4;
        const unsigned char* row = h1q + (size_t)s * 128;
        float q = pj[hd];
        unsigned u = *(const unsigned short*)&row[c0];
        f32x2 v = __builtin_amdgcn_cvt_pk_f32_fp8(u, false);
        f32x2 qq = {q, q};
        acc += qq * v;
        z += q;
    }
    float invz = 1.0f / z;
    float vx = acc.x * invz + b1[c0];
    float vy = acc.y * invz + b1[c0 + 1];
    vx = vx > 0.f ? vx : __expf(vx) - 1.0f;   // ELU
    vy = vy > 0.f ? vy : __expf(vy) - 1.0f;
    __hip_bfloat162 o;
    o.x = __float2bfloat16(vx);
    o.y = __float2bfloat16(vy);
    *(__hip_bfloat162*)&out1[(size_t)d * 128 + c0] = o;
}

// ---------------- layer-2 aggregation + head mean + b2 + log_softmax, fp8 gather ----------------

__global__ __launch_bounds__(256) void agg2_kernel(
        const unsigned char* __restrict__ h2q, const float* __restrict__ p4,
        const int* __restrict__ rowptr, const int* __restrict__ csr,
        const float* __restrict__ b2, float* __restrict__ out) {
    int d = blockIdx.x * 4 + (threadIdx.x >> 6);
    if (d >= N_NODES) return;
    int lane = threadIdx.x & 63;
    int ll = lane < 40 ? lane : 39;
    int hd = ll / 10;
    int voff = ll * 4;                         // byte offset within 160-B row
    f32x2 acc01 = {0.f, 0.f}, acc23 = {0.f, 0.f};
    float z = 0.f;
    int beg = __builtin_amdgcn_readfirstlane(rowptr[d]);
    int end = __builtin_amdgcn_readfirstlane(rowptr[d + 1]);
    int j = beg;
    for (; j + 3 < end; j += 4) {
        #pragma unroll
        for (int t = 0; t < 4; ++t) {
            int s = __builtin_amdgcn_readfirstlane(csr[j + t]);
            const float* pj = p4 + (size_t)(j + t) * 4;              // uniform
            const unsigned char* row = h2q + (size_t)s * 160;        // uniform
            float q = pj[hd];
            unsigned u = *(const unsigned*)&row[voff];
            f32x2 v01 = __builtin_amdgcn_cvt_pk_f32_fp8(u, false);
            f32x2 v23 = __builtin_amdgcn_cvt_pk_f32_fp8(u, true);
            f32x2 qq = {q, q};
            acc01 += qq * v01;
            acc23 += qq * v23;
            z += q;
        }
    }
    for (; j < end; ++j) {
        int s = __builtin_amdgcn_readfirstlane(csr[j]);
        const float* pj = p4 + (size_t)j * 4;
        const unsigned char* row = h2q + (size_t)s * 160;
        float q = pj[hd];
        unsigned u = *(const unsigned*)&row[voff];
        f32x2 v01 = __builtin_amdgcn_cvt_pk_f32_fp8(u, false);
        f32x2 v23 = __builtin_amdgcn_cvt_pk_f32_fp8(u, true);
        f32x2 qq = {q, q};
        acc01 += qq * v01;
        acc23 += qq * v23;
        z += q;
    }
    float invz = 1.0f / z;
    float rx = acc01.x * invz, ry = acc01.y * invz;
    float rz = acc23.x * invz, rw = acc23.y * invz;
    float sx = rx + __shfl(rx, lane + 10) + __shfl(rx, lane + 20) + __shfl(rx, lane + 30);
    float sy = ry + __shfl(ry, lane + 10) + __shfl(ry, lane + 20) + __shfl(ry, lane + 30);
    float sz = rz + __shfl(rz, lane + 10) + __shfl(rz, lane + 20) + __shfl(rz, lane + 30);
    float sw = rw + __shfl(rw, lane + 10) + __shfl(rw, lane + 20) + __shfl(rw, lane + 30);
    int lc = lane < 10 ? lane : 9;
    float4 bb = *(const float4*)&b2[lc * 4];
    bool own = lane < 10;
    float vx = own ? sx * 0.25f + bb.x : -1e30f;
    float vy = own ? sy * 0.25f + bb.y : -1e30f;
    float vz = own ? sz * 0.25f + bb.z : -1e30f;
    float vw = own ? sw * 0.25f + bb.w : -1e30f;
    float m = fmaxf(fmaxf(vx, vy), fmaxf(vz, vw));
    #pragma unroll
    for (int off = 1; off < 16; off <<= 1) m = fmaxf(m, __shfl_xor(m, off));
    float ssum = 0.f;
    if (own) {
        ssum = __expf(vx - m) + __expf(vy - m) + __expf(vz - m) + __expf(vw - m);
    }
    #pragma unroll
    for (int off = 1; off < 16; off <<= 1) ssum += __shfl_xor(ssum, off);
    float lse = m + __logf(ssum);
    if (own) {
        float4 o = {vx - lse, vy - lse, vz - lse, vw - lse};
        *(float4*)&out[(size_t)d * 40 + lane * 4] = o;
    }
}

// ---------------- launch ----------------

extern "C" void kernel_launch(void* const* d_in, const int* in_sizes, int n_in,
                              void* d_out, int out_size, void* d_ws, size_t ws_size,
                              hipStream_t stream) {
    const float* x   = (const float*)d_in[0];
    const int*   ei  = (const int*)d_in[1];
    const float* W1  = (const float*)d_in[2];
    const float* as1 = (const float*)d_in[3];
    const float* ad1 = (const float*)d_in[4];
    const float* b1  = (const float*)d_in[5];
    const float* W2  = (const float*)d_in[6];
    const float* as2 = (const float*)d_in[7];
    const float* ad2 = (const float*)d_in[8];
    const float* b2  = (const float*)d_in[9];
    float* out = (float*)d_out;

    char* ws = (char*)d_ws;
    size_t off = 0;
    auto alloc = [&](size_t bytes) {
        void* p = ws + off;
        off += (bytes + 255) & ~(size_t)255;
        return p;
    };
    __hip_bfloat16* h1b   = (__hip_bfloat16*)alloc((size_t)M_PAD * 128 * 2);
    __hip_bfloat16* out1b = (__hip_bfloat16*)alloc((size_t)M_PAD * 128 * 2);
    __hip_bfloat16* h2b   = (__hip_bfloat16*)alloc((size_t)M_PAD * 160 * 2);
    unsigned char*  h1q   = (unsigned char*)alloc((size_t)M_PAD * 128);
    unsigned char*  h2q   = (unsigned char*)alloc((size_t)M_PAD * 160);
    __hip_bfloat16* W1t   = (__hip_bfloat16*)alloc((size_t)128 * 128 * 2);
    __hip_bfloat16* W2t   = (__hip_bfloat16*)alloc((size_t)160 * 128 * 2);
    float* s_src1  = (float*)alloc((size_t)N_NODES * 4 * 4);
    float* s_dst1  = (float*)alloc((size_t)N_NODES * 4 * 4);
    float* s_src2  = (float*)alloc((size_t)N_NODES * 4 * 4);
    float* s_dst2  = (float*)alloc((size_t)N_NODES * 4 * 4);
    float* p4      = (float*)alloc((size_t)E_TOT * 4 * 4);
    int2*  tmp     = (int2*)alloc((size_t)E_TOT * 8);
    int*   rowptr  = (int*)alloc((size_t)(N_NODES + 1) * 4);
    int*   csr     = (int*)alloc((size_t)E_TOT * 4);
    int*   csrd    = (int*)alloc((size_t)E_TOT * 4);
    int*   cnt     = (int*)alloc((size_t)REP * BUCKETS * 4);
    int*   bsum    = (int*)alloc((size_t)BUCKETS * 4);
    int*   boff    = (int*)alloc((size_t)(BUCKETS + 1) * 4);

    // CSR build (sliced counting-sort partition; LDS cursors, no global atomics)
    slice_count_kernel<<<REP, 256, 0, stream>>>(ei, cnt);
    col_scan_kernel<<<BUCKETS, REP, 0, stream>>>(cnt, bsum);
    bucket_scan_kernel<<<1, 1024, 0, stream>>>(bsum, boff);
    bucket_scatter_kernel<<<REP, 256, 0, stream>>>(ei, cnt, boff, tmp);
    bucket_build_kernel<<<BUCKETS, 256, 0, stream>>>(tmp, boff, rowptr, csr, csrd);

    // dtype prep (weights only; x converted inside GEMM1)
    cvt_w_kernel<<<(128 * 128 + 128 * 160 + 255) / 256, 256, 0, stream>>>(W1, W1t, W2, W2t);

    // layer 1
    mfma_gemm_f32a_kernel<128><<<M_PAD / 128, 256, 0, stream>>>(x, W1t, h1b);
    score_kernel<32, 128><<<(N_NODES * 4 + 255) / 256, 256, 0, stream>>>(h1b, as1, ad1, s_src1, s_dst1, N_NODES);
    cvt_h_fp8_kernel<<<(N_NODES * 16 + 255) / 256, 256, 0, stream>>>(h1b, (unsigned*)h1q, N_NODES * 16);
    edge_p_kernel<<<(E_TOT + 255) / 256, 256, 0, stream>>>(csr, csrd, s_src1, s_dst1, p4, E_TOT);
    agg1_kernel<<<(N_NODES + 3) / 4, 256, 0, stream>>>(h1q, p4, rowptr, csr, b1, out1b);

    // layer 2
    mfma_gemm_kernel<160><<<M_PAD / 128, 256, 0, stream>>>(out1b, W2t, h2b);
    score_kernel<40, 160><<<(N_NODES * 4 + 255) / 256, 256, 0, stream>>>(h2b, as2, ad2, s_src2, s_dst2, N_NODES);
    cvt_h_fp8_kernel<<<(N_NODES * 20 + 255) / 256, 256, 0, stream>>>(h2b, (unsigned*)h2q, N_NODES * 20);
    edge_p_kernel<<<(E_TOT + 255) / 256, 256, 0, stream>>>(csr, csrd, s_src2, s_dst2, p4, E_TOT);
    agg2_kernel<<<(N_NODES + 3) / 4, 256, 0, stream>>>(h2q, p4, rowptr, csr, b2, out);
}

// Round 10
// 259.183 us; speedup vs baseline: 2.9982x; 1.1875x over previous
//
#include <hip/hip_runtime.h>
#include <hip/hip_bf16.h>

#define N_NODES 100000
#define M_PAD   100096            // 782 * 128, padded row count for MFMA GEMM
#define N_EDGES 1600000
#define E_TOT   (N_EDGES + N_NODES)   // + self loops
#define NEG_SLOPE 0.2f

#define G_NODES 128                                  // nodes per bucket (pow2)
#define BUCKETS ((N_NODES + G_NODES - 1) / G_NODES)  // 782
#define REP 512                                      // slices (one block each)
#define SLICE ((E_TOT + REP - 1) / REP)              // 3321 edges per slice

typedef __attribute__((ext_vector_type(8))) short s16x8;
typedef __attribute__((ext_vector_type(4))) float f32x4;
typedef __attribute__((ext_vector_type(2))) float f32x2;

__device__ __forceinline__ float lo16(unsigned u) { return __uint_as_float(u << 16); }
__device__ __forceinline__ float hi16(unsigned u) { return __uint_as_float(u & 0xffff0000u); }

__device__ __forceinline__ short f2bf(float f) {
    __hip_bfloat16 b = __float2bfloat16(f);
    return *(short*)&b;
}

// ---------------- CSR build: sliced counting-sort partition ----------------

__global__ __launch_bounds__(256) void slice_count_kernel(const int* __restrict__ ei,
                                                          int* __restrict__ cnt) {
    __shared__ int h[BUCKETS];
    for (int i = threadIdx.x; i < BUCKETS; i += 256) h[i] = 0;
    __syncthreads();
    int r = blockIdx.x;
    int lo = r * SLICE, hi = min(lo + SLICE, E_TOT);
    for (int e = lo + threadIdx.x; e < hi; e += 256) {
        int d = (e < N_EDGES) ? ei[N_EDGES + e] : e - N_EDGES;
        atomicAdd(&h[d >> 7], 1);
    }
    __syncthreads();
    for (int i = threadIdx.x; i < BUCKETS; i += 256)
        cnt[(size_t)r * BUCKETS + i] = h[i];
}

__global__ __launch_bounds__(REP) void col_scan_kernel(int* __restrict__ cnt,
                                                       int* __restrict__ bsum) {
    __shared__ int lds[REP];
    int b = blockIdx.x, tid = threadIdx.x;
    int v = cnt[(size_t)tid * BUCKETS + b];
    lds[tid] = v;
    __syncthreads();
    for (int off = 1; off < REP; off <<= 1) {
        int t = (tid >= off) ? lds[tid - off] : 0;
        __syncthreads();
        lds[tid] += t;
        __syncthreads();
    }
    cnt[(size_t)tid * BUCKETS + b] = lds[tid] - v;   // exclusive within column
    if (tid == REP - 1) bsum[b] = lds[tid];
}

__global__ __launch_bounds__(1024) void bucket_scan_kernel(const int* __restrict__ bsum,
                                                           int* __restrict__ boff) {
    __shared__ int lds[1024];
    int tid = threadIdx.x;
    int v = (tid < BUCKETS) ? bsum[tid] : 0;
    lds[tid] = v;
    __syncthreads();
    for (int off = 1; off < 1024; off <<= 1) {
        int t = (tid >= off) ? lds[tid - off] : 0;
        __syncthreads();
        lds[tid] += t;
        __syncthreads();
    }
    if (tid < BUCKETS) boff[tid] = lds[tid] - v;
    if (tid == 0) boff[BUCKETS] = E_TOT;
}

__global__ __launch_bounds__(256) void bucket_scatter_kernel(const int* __restrict__ ei,
                                                             const int* __restrict__ colx,
                                                             const int* __restrict__ boff,
                                                             int2* __restrict__ tmp) {
    __shared__ int lcur[BUCKETS];
    int r = blockIdx.x;
    for (int i = threadIdx.x; i < BUCKETS; i += 256)
        lcur[i] = boff[i] + colx[(size_t)r * BUCKETS + i];
    __syncthreads();
    int lo = r * SLICE, hi = min(lo + SLICE, E_TOT);
    for (int e = lo + threadIdx.x; e < hi; e += 256) {
        int s, d;
        if (e < N_EDGES) { s = ei[e]; d = ei[N_EDGES + e]; }
        else             { s = d = e - N_EDGES; }
        int pos = atomicAdd(&lcur[d >> 7], 1);
        tmp[pos] = make_int2(s, d);
    }
}

// per-bucket local count + scan -> rowptr; place csr only (no csrd needed)
__global__ __launch_bounds__(256) void bucket_build_kernel(const int2* __restrict__ tmp,
                                                           const int* __restrict__ boff,
                                                           int* __restrict__ rowptr,
                                                           int* __restrict__ csr) {
    __shared__ int hcnt[G_NODES];
    __shared__ int hoff[G_NODES];
    int b = blockIdx.x;
    int base = boff[b], cnt = boff[b + 1] - base;
    int tid = threadIdx.x;
    if (tid < G_NODES) hcnt[tid] = 0;
    __syncthreads();
    for (int i = tid; i < cnt; i += 256)
        atomicAdd(&hcnt[tmp[base + i].y & (G_NODES - 1)], 1);
    __syncthreads();
    if (tid < G_NODES) hoff[tid] = hcnt[tid];
    __syncthreads();
    for (int off = 1; off < G_NODES; off <<= 1) {
        int t = (tid < G_NODES && tid >= off) ? hoff[tid - off] : 0;
        __syncthreads();
        if (tid < G_NODES) hoff[tid] += t;
        __syncthreads();
    }
    if (tid < G_NODES) {
        int excl = hoff[tid] - hcnt[tid];
        int node = b * G_NODES + tid;
        if (node < N_NODES) rowptr[node] = base + excl;
        hcnt[tid] = excl;       // reuse as cursor
    }
    __syncthreads();
    for (int i = tid; i < cnt; i += 256) {
        int2 e = tmp[base + i];
        int pos = base + atomicAdd(&hcnt[e.y & (G_NODES - 1)], 1);
        csr[pos] = e.x;
    }
    if (b == 0 && tid == 0) rowptr[N_NODES] = E_TOT;
}

// ---------------- dtype conversion: both weights in one launch ----------------

__global__ void cvt_w_kernel(const float* __restrict__ W1, __hip_bfloat16* __restrict__ W1t,
                             const float* __restrict__ W2, __hip_bfloat16* __restrict__ W2t) {
    int idx = blockIdx.x * blockDim.x + threadIdx.x;
    if (idx < 128 * 128) {
        int k = idx >> 7, n = idx & 127;
        W1t[n * 128 + k] = __float2bfloat16(W1[idx]);
    } else if (idx < 128 * 128 + 128 * 160) {
        int i = idx - 128 * 128;
        int k = i / 160, n = i - k * 160;
        W2t[n * 128 + k] = __float2bfloat16(W2[i]);
    }
}

// ---------------- MFMA GEMM (layer 1): A f32 in-register cvt; OUTPUT fp8 ----------------

template<int NCOLS>
__global__ __launch_bounds__(256) void mfma_gemm_f32a_kernel(const float* __restrict__ A,
                                                             const __hip_bfloat16* __restrict__ Bt,
                                                             unsigned char* __restrict__ Cq) {
    constexpr int CG = NCOLS / 32;
    int wid = threadIdx.x >> 6;
    int lane = threadIdx.x & 63;
    int wr = wid >> 1, wc = wid & 1;
    int l15 = lane & 15, lk = lane >> 4;

    s16x8 bfrag[CG][4];
    #pragma unroll
    for (int cg = 0; cg < CG; ++cg) {
        int col = wc * (NCOLS / 2) + cg * 16 + l15;
        #pragma unroll
        for (int ks = 0; ks < 4; ++ks)
            bfrag[cg][ks] = *(const s16x8*)&Bt[col * 128 + ks * 32 + lk * 8];
    }
    int rowblk = blockIdx.x * 128;
    #pragma unroll
    for (int st = 0; st < 4; ++st) {
        int rbase = rowblk + st * 32 + wr * 16;
        int row = rbase + l15;
        bool ok = row < N_NODES;
        s16x8 afrag[4];
        #pragma unroll
        for (int ks = 0; ks < 4; ++ks) {
            if (ok) {
                float4 a0 = *(const float4*)&A[(size_t)row * 128 + ks * 32 + lk * 8];
                float4 a1 = *(const float4*)&A[(size_t)row * 128 + ks * 32 + lk * 8 + 4];
                s16x8 af;
                af[0] = f2bf(a0.x); af[1] = f2bf(a0.y); af[2] = f2bf(a0.z); af[3] = f2bf(a0.w);
                af[4] = f2bf(a1.x); af[5] = f2bf(a1.y); af[6] = f2bf(a1.z); af[7] = f2bf(a1.w);
                afrag[ks] = af;
            } else {
                afrag[ks] = (s16x8){0,0,0,0,0,0,0,0};
            }
        }
        f32x4 acc[CG];
        #pragma unroll
        for (int cg = 0; cg < CG; ++cg) acc[cg] = (f32x4){0.f, 0.f, 0.f, 0.f};
        #pragma unroll
        for (int ks = 0; ks < 4; ++ks) {
            #pragma unroll
            for (int cg = 0; cg < CG; ++cg)
                acc[cg] = __builtin_amdgcn_mfma_f32_16x16x32_bf16(afrag[ks], bfrag[cg][ks], acc[cg], 0, 0, 0);
        }
        #pragma unroll
        for (int cg = 0; cg < CG; ++cg) {
            int c = wc * (NCOLS / 2) + cg * 16 + l15;
            unsigned w01 = __builtin_amdgcn_cvt_pk_fp8_f32(acc[cg][0], acc[cg][1], 0, false);
            unsigned w23 = __builtin_amdgcn_cvt_pk_fp8_f32(acc[cg][2], acc[cg][3], 0, false);
            size_t base = (size_t)(rbase + lk * 4) * NCOLS + c;
            Cq[base]             = (unsigned char)(w01 & 0xff);
            Cq[base + NCOLS]     = (unsigned char)((w01 >> 8) & 0xff);
            Cq[base + 2 * NCOLS] = (unsigned char)(w23 & 0xff);
            Cq[base + 3 * NCOLS] = (unsigned char)((w23 >> 8) & 0xff);
        }
    }
}

// ---------------- MFMA GEMM (layer 2): bf16 A; OUTPUT fp8 ----------------

template<int NCOLS>
__global__ __launch_bounds__(256) void mfma_gemm_kernel(const __hip_bfloat16* __restrict__ A,
                                                        const __hip_bfloat16* __restrict__ Bt,
                                                        unsigned char* __restrict__ Cq) {
    constexpr int CG = NCOLS / 32;
    int wid = threadIdx.x >> 6;
    int lane = threadIdx.x & 63;
    int wr = wid >> 1, wc = wid & 1;
    int l15 = lane & 15, lk = lane >> 4;

    s16x8 bfrag[CG][4];
    #pragma unroll
    for (int cg = 0; cg < CG; ++cg) {
        int col = wc * (NCOLS / 2) + cg * 16 + l15;
        #pragma unroll
        for (int ks = 0; ks < 4; ++ks)
            bfrag[cg][ks] = *(const s16x8*)&Bt[col * 128 + ks * 32 + lk * 8];
    }
    int rowblk = blockIdx.x * 128;
    #pragma unroll
    for (int st = 0; st < 4; ++st) {
        int rbase = rowblk + st * 32 + wr * 16;
        s16x8 afrag[4];
        #pragma unroll
        for (int ks = 0; ks < 4; ++ks)
            afrag[ks] = *(const s16x8*)&A[(size_t)(rbase + l15) * 128 + ks * 32 + lk * 8];
        f32x4 acc[CG];
        #pragma unroll
        for (int cg = 0; cg < CG; ++cg) acc[cg] = (f32x4){0.f, 0.f, 0.f, 0.f};
        #pragma unroll
        for (int ks = 0; ks < 4; ++ks) {
            #pragma unroll
            for (int cg = 0; cg < CG; ++cg)
                acc[cg] = __builtin_amdgcn_mfma_f32_16x16x32_bf16(afrag[ks], bfrag[cg][ks], acc[cg], 0, 0, 0);
        }
        #pragma unroll
        for (int cg = 0; cg < CG; ++cg) {
            int c = wc * (NCOLS / 2) + cg * 16 + l15;
            unsigned w01 = __builtin_amdgcn_cvt_pk_fp8_f32(acc[cg][0], acc[cg][1], 0, false);
            unsigned w23 = __builtin_amdgcn_cvt_pk_fp8_f32(acc[cg][2], acc[cg][3], 0, false);
            size_t base = (size_t)(rbase + lk * 4) * NCOLS + c;
            Cq[base]             = (unsigned char)(w01 & 0xff);
            Cq[base + NCOLS]     = (unsigned char)((w01 >> 8) & 0xff);
            Cq[base + 2 * NCOLS] = (unsigned char)(w23 & 0xff);
            Cq[base + 3 * NCOLS] = (unsigned char)((w23 >> 8) & 0xff);
        }
    }
}

// ---------------- attention scores from fp8 h ----------------
// C = bytes per head, J = bytes per row

template<int C, int J>
__global__ void score_fp8_kernel(const unsigned char* __restrict__ hq,
                                 const float* __restrict__ att_src,
                                 const float* __restrict__ att_dst,
                                 float* __restrict__ s_src, float* __restrict__ s_dst, int n) {
    int idx = blockIdx.x * blockDim.x + threadIdx.x;   // node*4 + head
    if (idx >= n * 4) return;
    int node = idx >> 2, hd = idx & 3;
    const unsigned char* hp = hq + (size_t)node * J + hd * C;
    const float* as = att_src + hd * C;
    const float* ad = att_dst + hd * C;
    float ss = 0.f, sd = 0.f;
    #pragma unroll
    for (int c8 = 0; c8 < C / 8; ++c8) {
        uint2 u = *(const uint2*)&hp[c8 * 8];
        f32x2 v0 = __builtin_amdgcn_cvt_pk_f32_fp8(u.x, false);
        f32x2 v1 = __builtin_amdgcn_cvt_pk_f32_fp8(u.x, true);
        f32x2 v2 = __builtin_amdgcn_cvt_pk_f32_fp8(u.y, false);
        f32x2 v3 = __builtin_amdgcn_cvt_pk_f32_fp8(u.y, true);
        int c = c8 * 8;
        ss += v0.x * as[c]     + v0.y * as[c + 1] + v1.x * as[c + 2] + v1.y * as[c + 3]
            + v2.x * as[c + 4] + v2.y * as[c + 5] + v3.x * as[c + 6] + v3.y * as[c + 7];
        sd += v0.x * ad[c]     + v0.y * ad[c + 1] + v1.x * ad[c + 2] + v1.y * ad[c + 3]
            + v2.x * ad[c + 4] + v2.y * ad[c + 5] + v3.x * ad[c + 6] + v3.y * ad[c + 7];
    }
    s_src[idx] = ss;
    s_dst[idx] = sd;
}

// ---------------- layer-1 aggregation: inline softmax weight + fp8 gather ----------------

__global__ __launch_bounds__(256) void agg1_kernel(
        const unsigned char* __restrict__ h1q, const float* __restrict__ s_src,
        const float* __restrict__ s_dst, const int* __restrict__ rowptr,
        const int* __restrict__ csr, const float* __restrict__ b1,
        __hip_bfloat16* __restrict__ out1) {
    int d = blockIdx.x * 4 + (threadIdx.x >> 6);
    if (d >= N_NODES) return;
    int lane = threadIdx.x & 63;
    int c0 = lane * 2;
    int hd = lane >> 4;
    float sdst = s_dst[d * 4 + hd];
    f32x2 acc = {0.f, 0.f};
    float z = 0.f;
    int beg = __builtin_amdgcn_readfirstlane(rowptr[d]);
    int end = __builtin_amdgcn_readfirstlane(rowptr[d + 1]);
    int j = beg;
    for (; j + 3 < end; j += 4) {
        #pragma unroll
        for (int t = 0; t < 4; ++t) {
            int s = __builtin_amdgcn_readfirstlane(csr[j + t]);
            const float* srow = s_src + (size_t)s * 4;               // uniform
            const unsigned char* row = h1q + (size_t)s * 128;        // uniform
            float e = srow[hd] + sdst;
            e = fmaxf(e, NEG_SLOPE * e);
            float q = __expf(e);
            unsigned u = *(const unsigned short*)&row[c0];
            f32x2 v = __builtin_amdgcn_cvt_pk_f32_fp8(u, false);
            f32x2 qq = {q, q};
            acc += qq * v;
            z += q;
        }
    }
    for (; j < end; ++j) {
        int s = __builtin_amdgcn_readfirstlane(csr[j]);
        const float* srow = s_src + (size_t)s * 4;
        const unsigned char* row = h1q + (size_t)s * 128;
        float e = srow[hd] + sdst;
        e = fmaxf(e, NEG_SLOPE * e);
        float q = __expf(e);
        unsigned u = *(const unsigned short*)&row[c0];
        f32x2 v = __builtin_amdgcn_cvt_pk_f32_fp8(u, false);
        f32x2 qq = {q, q};
        acc += qq * v;
        z += q;
    }
    float invz = 1.0f / z;
    float vx = acc.x * invz + b1[c0];
    float vy = acc.y * invz + b1[c0 + 1];
    vx = vx > 0.f ? vx : __expf(vx) - 1.0f;   // ELU
    vy = vy > 0.f ? vy : __expf(vy) - 1.0f;
    __hip_bfloat162 o;
    o.x = __float2bfloat16(vx);
    o.y = __float2bfloat16(vy);
    *(__hip_bfloat162*)&out1[(size_t)d * 128 + c0] = o;
}

// ---------------- layer-2 aggregation + head mean + b2 + log_softmax ----------------

__global__ __launch_bounds__(256) void agg2_kernel(
        const unsigned char* __restrict__ h2q, const float* __restrict__ s_src,
        const float* __restrict__ s_dst, const int* __restrict__ rowptr,
        const int* __restrict__ csr, const float* __restrict__ b2,
        float* __restrict__ out) {
    int d = blockIdx.x * 4 + (threadIdx.x >> 6);
    if (d >= N_NODES) return;
    int lane = threadIdx.x & 63;
    int ll = lane < 40 ? lane : 39;
    int hd = ll / 10;
    int voff = ll * 4;                         // byte offset within 160-B row
    float sdst = s_dst[d * 4 + hd];
    f32x2 acc01 = {0.f, 0.f}, acc23 = {0.f, 0.f};
    float z = 0.f;
    int beg = __builtin_amdgcn_readfirstlane(rowptr[d]);
    int end = __builtin_amdgcn_readfirstlane(rowptr[d + 1]);
    int j = beg;
    for (; j + 3 < end; j += 4) {
        #pragma unroll
        for (int t = 0; t < 4; ++t) {
            int s = __builtin_amdgcn_readfirstlane(csr[j + t]);
            const float* srow = s_src + (size_t)s * 4;               // uniform
            const unsigned char* row = h2q + (size_t)s * 160;        // uniform
            float e = srow[hd] + sdst;
            e = fmaxf(e, NEG_SLOPE * e);
            float q = __expf(e);
            unsigned u = *(const unsigned*)&row[voff];
            f32x2 v01 = __builtin_amdgcn_cvt_pk_f32_fp8(u, false);
            f32x2 v23 = __builtin_amdgcn_cvt_pk_f32_fp8(u, true);
            f32x2 qq = {q, q};
            acc01 += qq * v01;
            acc23 += qq * v23;
            z += q;
        }
    }
    for (; j < end; ++j) {
        int s = __builtin_amdgcn_readfirstlane(csr[j]);
        const float* srow = s_src + (size_t)s * 4;
        const unsigned char* row = h2q + (size_t)s * 160;
        float e = srow[hd] + sdst;
        e = fmaxf(e, NEG_SLOPE * e);
        float q = __expf(e);
        unsigned u = *(const unsigned*)&row[voff];
        f32x2 v01 = __builtin_amdgcn_cvt_pk_f32_fp8(u, false);
        f32x2 v23 = __builtin_amdgcn_cvt_pk_f32_fp8(u, true);
        f32x2 qq = {q, q};
        acc01 += qq * v01;
        acc23 += qq * v23;
        z += q;
    }
    float invz = 1.0f / z;
    float rx = acc01.x * invz, ry = acc01.y * invz;
    float rz = acc23.x * invz, rw = acc23.y * invz;
    float sx = rx + __shfl(rx, lane + 10) + __shfl(rx, lane + 20) + __shfl(rx, lane + 30);
    float sy = ry + __shfl(ry, lane + 10) + __shfl(ry, lane + 20) + __shfl(ry, lane + 30);
    float sz = rz + __shfl(rz, lane + 10) + __shfl(rz, lane + 20) + __shfl(rz, lane + 30);
    float sw = rw + __shfl(rw, lane + 10) + __shfl(rw, lane + 20) + __shfl(rw, lane + 30);
    int lc = lane < 10 ? lane : 9;
    float4 bb = *(const float4*)&b2[lc * 4];
    bool own = lane < 10;
    float vx = own ? sx * 0.25f + bb.x : -1e30f;
    float vy = own ? sy * 0.25f + bb.y : -1e30f;
    float vz = own ? sz * 0.25f + bb.z : -1e30f;
    float vw = own ? sw * 0.25f + bb.w : -1e30f;
    float m = fmaxf(fmaxf(vx, vy), fmaxf(vz, vw));
    #pragma unroll
    for (int off = 1; off < 16; off <<= 1) m = fmaxf(m, __shfl_xor(m, off));
    float ssum = 0.f;
    if (own) {
        ssum = __expf(vx - m) + __expf(vy - m) + __expf(vz - m) + __expf(vw - m);
    }
    #pragma unroll
    for (int off = 1; off < 16; off <<= 1) ssum += __shfl_xor(ssum, off);
    float lse = m + __logf(ssum);
    if (own) {
        float4 o = {vx - lse, vy - lse, vz - lse, vw - lse};
        *(float4*)&out[(size_t)d * 40 + lane * 4] = o;
    }
}

// ---------------- launch ----------------

extern "C" void kernel_launch(void* const* d_in, const int* in_sizes, int n_in,
                              void* d_out, int out_size, void* d_ws, size_t ws_size,
                              hipStream_t stream) {
    const float* x   = (const float*)d_in[0];
    const int*   ei  = (const int*)d_in[1];
    const float* W1  = (const float*)d_in[2];
    const float* as1 = (const float*)d_in[3];
    const float* ad1 = (const float*)d_in[4];
    const float* b1  = (const float*)d_in[5];
    const float* W2  = (const float*)d_in[6];
    const float* as2 = (const float*)d_in[7];
    const float* ad2 = (const float*)d_in[8];
    const float* b2  = (const float*)d_in[9];
    float* out = (float*)d_out;

    char* ws = (char*)d_ws;
    size_t off = 0;
    auto alloc = [&](size_t bytes) {
        void* p = ws + off;
        off += (bytes + 255) & ~(size_t)255;
        return p;
    };
    unsigned char*  h1q   = (unsigned char*)alloc((size_t)M_PAD * 128);
    unsigned char*  h2q   = (unsigned char*)alloc((size_t)M_PAD * 160);
    __hip_bfloat16* out1b = (__hip_bfloat16*)alloc((size_t)M_PAD * 128 * 2);
    __hip_bfloat16* W1t   = (__hip_bfloat16*)alloc((size_t)128 * 128 * 2);
    __hip_bfloat16* W2t   = (__hip_bfloat16*)alloc((size_t)160 * 128 * 2);
    float* s_src1  = (float*)alloc((size_t)N_NODES * 4 * 4);
    float* s_dst1  = (float*)alloc((size_t)N_NODES * 4 * 4);
    float* s_src2  = (float*)alloc((size_t)N_NODES * 4 * 4);
    float* s_dst2  = (float*)alloc((size_t)N_NODES * 4 * 4);
    int2*  tmp     = (int2*)alloc((size_t)E_TOT * 8);
    int*   rowptr  = (int*)alloc((size_t)(N_NODES + 1) * 4);
    int*   csr     = (int*)alloc((size_t)E_TOT * 4);
    int*   cnt     = (int*)alloc((size_t)REP * BUCKETS * 4);
    int*   bsum    = (int*)alloc((size_t)BUCKETS * 4);
    int*   boff    = (int*)alloc((size_t)(BUCKETS + 1) * 4);

    // CSR build (sliced counting-sort partition; LDS cursors, no global atomics)
    slice_count_kernel<<<REP, 256, 0, stream>>>(ei, cnt);
    col_scan_kernel<<<BUCKETS, REP, 0, stream>>>(cnt, bsum);
    bucket_scan_kernel<<<1, 1024, 0, stream>>>(bsum, boff);
    bucket_scatter_kernel<<<REP, 256, 0, stream>>>(ei, cnt, boff, tmp);
    bucket_build_kernel<<<BUCKETS, 256, 0, stream>>>(tmp, boff, rowptr, csr);

    // dtype prep (weights only; x converted inside GEMM1)
    cvt_w_kernel<<<(128 * 128 + 128 * 160 + 255) / 256, 256, 0, stream>>>(W1, W1t, W2, W2t);

    // layer 1
    mfma_gemm_f32a_kernel<128><<<M_PAD / 128, 256, 0, stream>>>(x, W1t, h1q);
    score_fp8_kernel<32, 128><<<(N_NODES * 4 + 255) / 256, 256, 0, stream>>>(h1q, as1, ad1, s_src1, s_dst1, N_NODES);
    agg1_kernel<<<(N_NODES + 3) / 4, 256, 0, stream>>>(h1q, s_src1, s_dst1, rowptr, csr, b1, out1b);

    // layer 2
    mfma_gemm_kernel<160><<<M_PAD / 128, 256, 0, stream>>>(out1b, W2t, h2q);
    score_fp8_kernel<40, 160><<<(N_NODES * 4 + 255) / 256, 256, 0, stream>>>(h2q, as2, ad2, s_src2, s_dst2, N_NODES);
    agg2_kernel<<<(N_NODES + 3) / 4, 256, 0, stream>>>(h2q, s_src2, s_dst2, rowptr, csr, b2, out);
}

// Round 11
// 249.896 us; speedup vs baseline: 3.1096x; 1.0372x over previous
//
#include <hip/hip_runtime.h>
#include <hip/hip_bf16.h>

#define N_NODES 100000
#define M_PAD   100096            // 782 * 128, padded row count for MFMA GEMM
#define N_EDGES 1600000
#define E_TOT   (N_EDGES + N_NODES)   // + self loops
#define NEG_SLOPE 0.2f

#define G_NODES 128                                  // nodes per bucket (pow2)
#define BUCKETS ((N_NODES + G_NODES - 1) / G_NODES)  // 782
#define REP 512                                      // slices (one block each)
#define SLICE ((E_TOT + REP - 1) / REP)              // 3321 edges per slice

typedef __attribute__((ext_vector_type(8))) short s16x8;
typedef __attribute__((ext_vector_type(4))) float f32x4;
typedef __attribute__((ext_vector_type(2))) float f32x2;

__device__ __forceinline__ float lo16(unsigned u) { return __uint_as_float(u << 16); }
__device__ __forceinline__ float hi16(unsigned u) { return __uint_as_float(u & 0xffff0000u); }

__device__ __forceinline__ short f2bf(float f) {
    __hip_bfloat16 b = __float2bfloat16(f);
    return *(short*)&b;
}

// ---------------- CSR build: sliced counting-sort partition ----------------

__global__ __launch_bounds__(256) void slice_count_kernel(const int* __restrict__ ei,
                                                          int* __restrict__ cnt) {
    __shared__ int h[BUCKETS];
    for (int i = threadIdx.x; i < BUCKETS; i += 256) h[i] = 0;
    __syncthreads();
    int r = blockIdx.x;
    int lo = r * SLICE, hi = min(lo + SLICE, E_TOT);
    for (int e = lo + threadIdx.x; e < hi; e += 256) {
        int d = (e < N_EDGES) ? ei[N_EDGES + e] : e - N_EDGES;
        atomicAdd(&h[d >> 7], 1);
    }
    __syncthreads();
    for (int i = threadIdx.x; i < BUCKETS; i += 256)
        cnt[(size_t)r * BUCKETS + i] = h[i];
}

__global__ __launch_bounds__(REP) void col_scan_kernel(int* __restrict__ cnt,
                                                       int* __restrict__ bsum) {
    __shared__ int lds[REP];
    int b = blockIdx.x, tid = threadIdx.x;
    int v = cnt[(size_t)tid * BUCKETS + b];
    lds[tid] = v;
    __syncthreads();
    for (int off = 1; off < REP; off <<= 1) {
        int t = (tid >= off) ? lds[tid - off] : 0;
        __syncthreads();
        lds[tid] += t;
        __syncthreads();
    }
    cnt[(size_t)tid * BUCKETS + b] = lds[tid] - v;   // exclusive within column
    if (tid == REP - 1) bsum[b] = lds[tid];
}

__global__ __launch_bounds__(1024) void bucket_scan_kernel(const int* __restrict__ bsum,
                                                           int* __restrict__ boff) {
    __shared__ int lds[1024];
    int tid = threadIdx.x;
    int v = (tid < BUCKETS) ? bsum[tid] : 0;
    lds[tid] = v;
    __syncthreads();
    for (int off = 1; off < 1024; off <<= 1) {
        int t = (tid >= off) ? lds[tid - off] : 0;
        __syncthreads();
        lds[tid] += t;
        __syncthreads();
    }
    if (tid < BUCKETS) boff[tid] = lds[tid] - v;
    if (tid == 0) boff[BUCKETS] = E_TOT;
}

// scatter packed (s<<7 | d&127) into bucket-contiguous tmp; LDS cursors
__global__ __launch_bounds__(256) void bucket_scatter_kernel(const int* __restrict__ ei,
                                                             const int* __restrict__ colx,
                                                             const int* __restrict__ boff,
                                                             int* __restrict__ tmp) {
    __shared__ int lcur[BUCKETS];
    int r = blockIdx.x;
    for (int i = threadIdx.x; i < BUCKETS; i += 256)
        lcur[i] = boff[i] + colx[(size_t)r * BUCKETS + i];
    __syncthreads();
    int lo = r * SLICE, hi = min(lo + SLICE, E_TOT);
    for (int e = lo + threadIdx.x; e < hi; e += 256) {
        int s, d;
        if (e < N_EDGES) { s = ei[e]; d = ei[N_EDGES + e]; }
        else             { s = d = e - N_EDGES; }
        int pos = atomicAdd(&lcur[d >> 7], 1);
        tmp[pos] = (s << 7) | (d & (G_NODES - 1));
    }
}

// per-bucket local count + scan -> rowptr; place csr (src only)
__global__ __launch_bounds__(256) void bucket_build_kernel(const int* __restrict__ tmp,
                                                           const int* __restrict__ boff,
                                                           int* __restrict__ rowptr,
                                                           int* __restrict__ csr) {
    __shared__ int hcnt[G_NODES];
    __shared__ int hoff[G_NODES];
    int b = blockIdx.x;
    int base = boff[b], cnt = boff[b + 1] - base;
    int tid = threadIdx.x;
    if (tid < G_NODES) hcnt[tid] = 0;
    __syncthreads();
    for (int i = tid; i < cnt; i += 256)
        atomicAdd(&hcnt[tmp[base + i] & (G_NODES - 1)], 1);
    __syncthreads();
    if (tid < G_NODES) hoff[tid] = hcnt[tid];
    __syncthreads();
    for (int off = 1; off < G_NODES; off <<= 1) {
        int t = (tid < G_NODES && tid >= off) ? hoff[tid - off] : 0;
        __syncthreads();
        if (tid < G_NODES) hoff[tid] += t;
        __syncthreads();
    }
    if (tid < G_NODES) {
        int excl = hoff[tid] - hcnt[tid];
        int node = b * G_NODES + tid;
        if (node < N_NODES) rowptr[node] = base + excl;
        hcnt[tid] = excl;       // reuse as cursor
    }
    __syncthreads();
    for (int i = tid; i < cnt; i += 256) {
        int v = tmp[base + i];
        int pos = base + atomicAdd(&hcnt[v & (G_NODES - 1)], 1);
        csr[pos] = v >> 7;
    }
    if (b == 0 && tid == 0) rowptr[N_NODES] = E_TOT;
}

// ---------------- dtype conversion: both weights in one launch ----------------

__global__ void cvt_w_kernel(const float* __restrict__ W1, __hip_bfloat16* __restrict__ W1t,
                             const float* __restrict__ W2, __hip_bfloat16* __restrict__ W2t) {
    int idx = blockIdx.x * blockDim.x + threadIdx.x;
    if (idx < 128 * 128) {
        int k = idx >> 7, n = idx & 127;
        W1t[n * 128 + k] = __float2bfloat16(W1[idx]);
    } else if (idx < 128 * 128 + 128 * 160) {
        int i = idx - 128 * 128;
        int k = i / 160, n = i - k * 160;
        W2t[n * 128 + k] = __float2bfloat16(W2[i]);
    }
}

// ---------------- MFMA GEMM (layer 1): A f32 in-register cvt; OUTPUT fp8 ----------------

template<int NCOLS>
__global__ __launch_bounds__(256) void mfma_gemm_f32a_kernel(const float* __restrict__ A,
                                                             const __hip_bfloat16* __restrict__ Bt,
                                                             unsigned char* __restrict__ Cq) {
    constexpr int CG = NCOLS / 32;
    int wid = threadIdx.x >> 6;
    int lane = threadIdx.x & 63;
    int wr = wid >> 1, wc = wid & 1;
    int l15 = lane & 15, lk = lane >> 4;

    s16x8 bfrag[CG][4];
    #pragma unroll
    for (int cg = 0; cg < CG; ++cg) {
        int col = wc * (NCOLS / 2) + cg * 16 + l15;
        #pragma unroll
        for (int ks = 0; ks < 4; ++ks)
            bfrag[cg][ks] = *(const s16x8*)&Bt[col * 128 + ks * 32 + lk * 8];
    }
    int rowblk = blockIdx.x * 128;
    #pragma unroll
    for (int st = 0; st < 4; ++st) {
        int rbase = rowblk + st * 32 + wr * 16;
        int row = rbase + l15;
        bool ok = row < N_NODES;
        s16x8 afrag[4];
        #pragma unroll
        for (int ks = 0; ks < 4; ++ks) {
            if (ok) {
                float4 a0 = *(const float4*)&A[(size_t)row * 128 + ks * 32 + lk * 8];
                float4 a1 = *(const float4*)&A[(size_t)row * 128 + ks * 32 + lk * 8 + 4];
                s16x8 af;
                af[0] = f2bf(a0.x); af[1] = f2bf(a0.y); af[2] = f2bf(a0.z); af[3] = f2bf(a0.w);
                af[4] = f2bf(a1.x); af[5] = f2bf(a1.y); af[6] = f2bf(a1.z); af[7] = f2bf(a1.w);
                afrag[ks] = af;
            } else {
                afrag[ks] = (s16x8){0,0,0,0,0,0,0,0};
            }
        }
        f32x4 acc[CG];
        #pragma unroll
        for (int cg = 0; cg < CG; ++cg) acc[cg] = (f32x4){0.f, 0.f, 0.f, 0.f};
        #pragma unroll
        for (int ks = 0; ks < 4; ++ks) {
            #pragma unroll
            for (int cg = 0; cg < CG; ++cg)
                acc[cg] = __builtin_amdgcn_mfma_f32_16x16x32_bf16(afrag[ks], bfrag[cg][ks], acc[cg], 0, 0, 0);
        }
        #pragma unroll
        for (int cg = 0; cg < CG; ++cg) {
            int c = wc * (NCOLS / 2) + cg * 16 + l15;
            unsigned w01 = __builtin_amdgcn_cvt_pk_fp8_f32(acc[cg][0], acc[cg][1], 0, false);
            unsigned w23 = __builtin_amdgcn_cvt_pk_fp8_f32(acc[cg][2], acc[cg][3], 0, false);
            size_t base = (size_t)(rbase + lk * 4) * NCOLS + c;
            Cq[base]             = (unsigned char)(w01 & 0xff);
            Cq[base + NCOLS]     = (unsigned char)((w01 >> 8) & 0xff);
            Cq[base + 2 * NCOLS] = (unsigned char)(w23 & 0xff);
            Cq[base + 3 * NCOLS] = (unsigned char)((w23 >> 8) & 0xff);
        }
    }
}

// ---------------- MFMA GEMM (layer 2): bf16 A; OUTPUT fp8 ----------------

template<int NCOLS>
__global__ __launch_bounds__(256) void mfma_gemm_kernel(const __hip_bfloat16* __restrict__ A,
                                                        const __hip_bfloat16* __restrict__ Bt,
                                                        unsigned char* __restrict__ Cq) {
    constexpr int CG = NCOLS / 32;
    int wid = threadIdx.x >> 6;
    int lane = threadIdx.x & 63;
    int wr = wid >> 1, wc = wid & 1;
    int l15 = lane & 15, lk = lane >> 4;

    s16x8 bfrag[CG][4];
    #pragma unroll
    for (int cg = 0; cg < CG; ++cg) {
        int col = wc * (NCOLS / 2) + cg * 16 + l15;
        #pragma unroll
        for (int ks = 0; ks < 4; ++ks)
            bfrag[cg][ks] = *(const s16x8*)&Bt[col * 128 + ks * 32 + lk * 8];
    }
    int rowblk = blockIdx.x * 128;
    #pragma unroll
    for (int st = 0; st < 4; ++st) {
        int rbase = rowblk + st * 32 + wr * 16;
        s16x8 afrag[4];
        #pragma unroll
        for (int ks = 0; ks < 4; ++ks)
            afrag[ks] = *(const s16x8*)&A[(size_t)(rbase + l15) * 128 + ks * 32 + lk * 8];
        f32x4 acc[CG];
        #pragma unroll
        for (int cg = 0; cg < CG; ++cg) acc[cg] = (f32x4){0.f, 0.f, 0.f, 0.f};
        #pragma unroll
        for (int ks = 0; ks < 4; ++ks) {
            #pragma unroll
            for (int cg = 0; cg < CG; ++cg)
                acc[cg] = __builtin_amdgcn_mfma_f32_16x16x32_bf16(afrag[ks], bfrag[cg][ks], acc[cg], 0, 0, 0);
        }
        #pragma unroll
        for (int cg = 0; cg < CG; ++cg) {
            int c = wc * (NCOLS / 2) + cg * 16 + l15;
            unsigned w01 = __builtin_amdgcn_cvt_pk_fp8_f32(acc[cg][0], acc[cg][1], 0, false);
            unsigned w23 = __builtin_amdgcn_cvt_pk_fp8_f32(acc[cg][2], acc[cg][3], 0, false);
            size_t base = (size_t)(rbase + lk * 4) * NCOLS + c;
            Cq[base]             = (unsigned char)(w01 & 0xff);
            Cq[base + NCOLS]     = (unsigned char)((w01 >> 8) & 0xff);
            Cq[base + 2 * NCOLS] = (unsigned char)(w23 & 0xff);
            Cq[base + 3 * NCOLS] = (unsigned char)((w23 >> 8) & 0xff);
        }
    }
}

// ---------------- attention scores from fp8 h ----------------

template<int C, int J>
__global__ void score_fp8_kernel(const unsigned char* __restrict__ hq,
                                 const float* __restrict__ att_src,
                                 const float* __restrict__ att_dst,
                                 float* __restrict__ s_src, float* __restrict__ s_dst, int n) {
    int idx = blockIdx.x * blockDim.x + threadIdx.x;   // node*4 + head
    if (idx >= n * 4) return;
    int node = idx >> 2, hd = idx & 3;
    const unsigned char* hp = hq + (size_t)node * J + hd * C;
    const float* as = att_src + hd * C;
    const float* ad = att_dst + hd * C;
    float ss = 0.f, sd = 0.f;
    #pragma unroll
    for (int c8 = 0; c8 < C / 8; ++c8) {
        uint2 u = *(const uint2*)&hp[c8 * 8];
        f32x2 v0 = __builtin_amdgcn_cvt_pk_f32_fp8(u.x, false);
        f32x2 v1 = __builtin_amdgcn_cvt_pk_f32_fp8(u.x, true);
        f32x2 v2 = __builtin_amdgcn_cvt_pk_f32_fp8(u.y, false);
        f32x2 v3 = __builtin_amdgcn_cvt_pk_f32_fp8(u.y, true);
        int c = c8 * 8;
        ss += v0.x * as[c]     + v0.y * as[c + 1] + v1.x * as[c + 2] + v1.y * as[c + 3]
            + v2.x * as[c + 4] + v2.y * as[c + 5] + v3.x * as[c + 6] + v3.y * as[c + 7];
        sd += v0.x * ad[c]     + v0.y * ad[c + 1] + v1.x * ad[c + 2] + v1.y * ad[c + 3]
            + v2.x * ad[c + 4] + v2.y * ad[c + 5] + v3.x * ad[c + 6] + v3.y * ad[c + 7];
    }
    s_src[idx] = ss;
    s_dst[idx] = sd;
}

// ---------------- layer-1 aggregation: cooperative q + fp8 gather ----------------
// Per 8-edge group: lanes (4*edge+head) compute q once; consumers ds_bpermute it.

__global__ __launch_bounds__(256) void agg1_kernel(
        const unsigned char* __restrict__ h1q, const float* __restrict__ s_src,
        const float* __restrict__ s_dst, const int* __restrict__ rowptr,
        const int* __restrict__ csr, const float* __restrict__ b1,
        __hip_bfloat16* __restrict__ out1) {
    int d = blockIdx.x * 4 + (threadIdx.x >> 6);
    if (d >= N_NODES) return;
    int lane = threadIdx.x & 63;
    int c0 = lane * 2;
    int hd = lane >> 4;
    int bp = hd << 2;                                  // bpermute byte base
    int eg = (lane >> 2) & 7;                          // edge slot this lane scores
    float sdall = s_dst[d * 4 + (lane & 3)];
    f32x2 acc = {0.f, 0.f};
    float z = 0.f;
    int beg = __builtin_amdgcn_readfirstlane(rowptr[d]);
    int end = __builtin_amdgcn_readfirstlane(rowptr[d + 1]);
    for (int j = beg; j < end; j += 8) {
        int cnt = end - j;
        int se = csr[min(j + eg, end - 1)];
        float ee = s_src[(size_t)se * 4 + (lane & 3)] + sdall;
        ee = fmaxf(ee, NEG_SLOPE * ee);
        float qv = (eg < cnt) ? __expf(ee) : 0.f;
        int qbits = __float_as_int(qv);
        #pragma unroll
        for (int t = 0; t < 8; ++t) {
            float q = __int_as_float(__builtin_amdgcn_ds_bpermute(bp + t * 16, qbits));
            int s = __builtin_amdgcn_readfirstlane(csr[min(j + t, end - 1)]);
            const unsigned char* row = h1q + (size_t)s * 128;
            unsigned u = *(const unsigned short*)&row[c0];
            f32x2 v = __builtin_amdgcn_cvt_pk_f32_fp8(u, false);
            f32x2 qq = {q, q};
            acc += qq * v;
            z += q;
        }
    }
    float invz = 1.0f / z;
    float vx = acc.x * invz + b1[c0];
    float vy = acc.y * invz + b1[c0 + 1];
    vx = vx > 0.f ? vx : __expf(vx) - 1.0f;   // ELU
    vy = vy > 0.f ? vy : __expf(vy) - 1.0f;
    __hip_bfloat162 o;
    o.x = __float2bfloat16(vx);
    o.y = __float2bfloat16(vy);
    *(__hip_bfloat162*)&out1[(size_t)d * 128 + c0] = o;
}

// ---------------- layer-2 aggregation + head mean + b2 + log_softmax ----------------

__global__ __launch_bounds__(256) void agg2_kernel(
        const unsigned char* __restrict__ h2q, const float* __restrict__ s_src,
        const float* __restrict__ s_dst, const int* __restrict__ rowptr,
        const int* __restrict__ csr, const float* __restrict__ b2,
        float* __restrict__ out) {
    int d = blockIdx.x * 4 + (threadIdx.x >> 6);
    if (d >= N_NODES) return;
    int lane = threadIdx.x & 63;
    int ll = lane < 40 ? lane : 39;
    int hd = ll / 10;
    int bp = hd << 2;
    int eg = (lane >> 2) & 7;
    int voff = ll * 4;                         // byte offset within 160-B row
    float sdall = s_dst[d * 4 + (lane & 3)];
    f32x2 acc01 = {0.f, 0.f}, acc23 = {0.f, 0.f};
    float z = 0.f;
    int beg = __builtin_amdgcn_readfirstlane(rowptr[d]);
    int end = __builtin_amdgcn_readfirstlane(rowptr[d + 1]);
    for (int j = beg; j < end; j += 8) {
        int cnt = end - j;
        int se = csr[min(j + eg, end - 1)];
        float ee = s_src[(size_t)se * 4 + (lane & 3)] + sdall;
        ee = fmaxf(ee, NEG_SLOPE * ee);
        float qv = (eg < cnt) ? __expf(ee) : 0.f;
        int qbits = __float_as_int(qv);
        #pragma unroll
        for (int t = 0; t < 8; ++t) {
            float q = __int_as_float(__builtin_amdgcn_ds_bpermute(bp + t * 16, qbits));
            int s = __builtin_amdgcn_readfirstlane(csr[min(j + t, end - 1)]);
            const unsigned char* row = h2q + (size_t)s * 160;
            unsigned u = *(const unsigned*)&row[voff];
            f32x2 v01 = __builtin_amdgcn_cvt_pk_f32_fp8(u, false);
            f32x2 v23 = __builtin_amdgcn_cvt_pk_f32_fp8(u, true);
            f32x2 qq = {q, q};
            acc01 += qq * v01;
            acc23 += qq * v23;
            z += q;
        }
    }
    float invz = 1.0f / z;
    float rx = acc01.x * invz, ry = acc01.y * invz;
    float rz = acc23.x * invz, rw = acc23.y * invz;
    float sx = rx + __shfl(rx, lane + 10) + __shfl(rx, lane + 20) + __shfl(rx, lane + 30);
    float sy = ry + __shfl(ry, lane + 10) + __shfl(ry, lane + 20) + __shfl(ry, lane + 30);
    float sz = rz + __shfl(rz, lane + 10) + __shfl(rz, lane + 20) + __shfl(rz, lane + 30);
    float sw = rw + __shfl(rw, lane + 10) + __shfl(rw, lane + 20) + __shfl(rw, lane + 30);
    int lc = lane < 10 ? lane : 9;
    float4 bb = *(const float4*)&b2[lc * 4];
    bool own = lane < 10;
    float vx = own ? sx * 0.25f + bb.x : -1e30f;
    float vy = own ? sy * 0.25f + bb.y : -1e30f;
    float vz = own ? sz * 0.25f + bb.z : -1e30f;
    float vw = own ? sw * 0.25f + bb.w : -1e30f;
    float m = fmaxf(fmaxf(vx, vy), fmaxf(vz, vw));
    #pragma unroll
    for (int off = 1; off < 16; off <<= 1) m = fmaxf(m, __shfl_xor(m, off));
    float ssum = 0.f;
    if (own) {
        ssum = __expf(vx - m) + __expf(vy - m) + __expf(vz - m) + __expf(vw - m);
    }
    #pragma unroll
    for (int off = 1; off < 16; off <<= 1) ssum += __shfl_xor(ssum, off);
    float lse = m + __logf(ssum);
    if (own) {
        float4 o = {vx - lse, vy - lse, vz - lse, vw - lse};
        *(float4*)&out[(size_t)d * 40 + lane * 4] = o;
    }
}

// ---------------- launch ----------------

extern "C" void kernel_launch(void* const* d_in, const int* in_sizes, int n_in,
                              void* d_out, int out_size, void* d_ws, size_t ws_size,
                              hipStream_t stream) {
    const float* x   = (const float*)d_in[0];
    const int*   ei  = (const int*)d_in[1];
    const float* W1  = (const float*)d_in[2];
    const float* as1 = (const float*)d_in[3];
    const float* ad1 = (const float*)d_in[4];
    const float* b1  = (const float*)d_in[5];
    const float* W2  = (const float*)d_in[6];
    const float* as2 = (const float*)d_in[7];
    const float* ad2 = (const float*)d_in[8];
    const float* b2  = (const float*)d_in[9];
    float* out = (float*)d_out;

    char* ws = (char*)d_ws;
    size_t off = 0;
    auto alloc = [&](size_t bytes) {
        void* p = ws + off;
        off += (bytes + 255) & ~(size_t)255;
        return p;
    };
    unsigned char*  h1q   = (unsigned char*)alloc((size_t)M_PAD * 128);
    unsigned char*  h2q   = (unsigned char*)alloc((size_t)M_PAD * 160);
    __hip_bfloat16* out1b = (__hip_bfloat16*)alloc((size_t)M_PAD * 128 * 2);
    __hip_bfloat16* W1t   = (__hip_bfloat16*)alloc((size_t)128 * 128 * 2);
    __hip_bfloat16* W2t   = (__hip_bfloat16*)alloc((size_t)160 * 128 * 2);
    float* s_src1  = (float*)alloc((size_t)N_NODES * 4 * 4);
    float* s_dst1  = (float*)alloc((size_t)N_NODES * 4 * 4);
    float* s_src2  = (float*)alloc((size_t)N_NODES * 4 * 4);
    float* s_dst2  = (float*)alloc((size_t)N_NODES * 4 * 4);
    int*   tmp     = (int*)alloc((size_t)E_TOT * 4);
    int*   rowptr  = (int*)alloc((size_t)(N_NODES + 1) * 4);
    int*   csr     = (int*)alloc((size_t)E_TOT * 4);
    int*   cnt     = (int*)alloc((size_t)REP * BUCKETS * 4);
    int*   bsum    = (int*)alloc((size_t)BUCKETS * 4);
    int*   boff    = (int*)alloc((size_t)(BUCKETS + 1) * 4);

    // CSR build (sliced counting-sort partition; LDS cursors, packed tmp)
    slice_count_kernel<<<REP, 256, 0, stream>>>(ei, cnt);
    col_scan_kernel<<<BUCKETS, REP, 0, stream>>>(cnt, bsum);
    bucket_scan_kernel<<<1, 1024, 0, stream>>>(bsum, boff);
    bucket_scatter_kernel<<<REP, 256, 0, stream>>>(ei, cnt, boff, tmp);
    bucket_build_kernel<<<BUCKETS, 256, 0, stream>>>(tmp, boff, rowptr, csr);

    // dtype prep (weights only; x converted inside GEMM1)
    cvt_w_kernel<<<(128 * 128 + 128 * 160 + 255) / 256, 256, 0, stream>>>(W1, W1t, W2, W2t);

    // layer 1
    mfma_gemm_f32a_kernel<128><<<M_PAD / 128, 256, 0, stream>>>(x, W1t, h1q);
    score_fp8_kernel<32, 128><<<(N_NODES * 4 + 255) / 256, 256, 0, stream>>>(h1q, as1, ad1, s_src1, s_dst1, N_NODES);
    agg1_kernel<<<(N_NODES + 3) / 4, 256, 0, stream>>>(h1q, s_src1, s_dst1, rowptr, csr, b1, out1b);

    // layer 2
    mfma_gemm_kernel<160><<<M_PAD / 128, 256, 0, stream>>>(out1b, W2t, h2q);
    score_fp8_kernel<40, 160><<<(N_NODES * 4 + 255) / 256, 256, 0, stream>>>(h2q, as2, ad2, s_src2, s_dst2, N_NODES);
    agg2_kernel<<<(N_NODES + 3) / 4, 256, 0, stream>>>(h2q, s_src2, s_dst2, rowptr, csr, b2, out);
}